// Round 2
// baseline (1806.316 us; speedup 1.0000x reference)
//
#include <hip/hip_runtime.h>
#include <math.h>

// NoiScaleModule: B=128, C=32(seq), S=512(d_model), EMB=256, NHEAD=8, DFF=2048
// All tensors FLOAT32 (reference dtype). Outputs concat flat:
//   res[2M], down_x[2M], fa[2M], up[2M]  (2M = 4096*512 f32 each)
//
// Simplifications vs reference:
//  - 'high' freq branch is dead code (xcat == low), h1/hb1 unused.
//  - rfft folded into low-projection:  low_pre = x @ Wa^T + [lb1_re|lb1_im]
//  - irfft+linear_change folded:       fa = LL @ Wm^T + lc_b

#define NROW 4096          // B*C rows
#define NOUT 2097152       // 4096*512

// ---------------- prep: cos/sin tables  tab[n][k], n<512, k<256 ----------------
__global__ __launch_bounds__(256) void tab_kernel(float* __restrict__ tabC, float* __restrict__ tabS)
{
    int n = blockIdx.x;          // 0..511
    int k = threadIdx.x;         // 0..255
    int m = (n * k) & 511;       // theta has period 512 in n*k
    float th = (float)m * 0.01227184630308513f;  // 2*pi/512
    float s, c;
    sincosf(th, &s, &c);
    tabC[n * 256 + k] = c;
    tabS[n * 256 + k] = s;
}

// Wa[ep][n]: ep<256 -> re coeffs, ep>=256 -> im coeffs.
// rfft(ortho): ReX_k = inv*sum_n x cos(2pi nk/512), ImX_k = -inv*sum_n x sin(2pi nk/512)
__global__ __launch_bounds__(256) void wa_kernel(const float* __restrict__ l1_re, const float* __restrict__ l1_im,
                                                 const float* __restrict__ tabC, const float* __restrict__ tabS,
                                                 float* __restrict__ Wa)
{
    int n  = blockIdx.x;                       // 0..511
    int ep = blockIdx.y * 256 + threadIdx.x;   // 0..511
    const float inv = 0.04419417382415922f;    // 1/sqrt(512)
    float acc = 0.f;
    if (ep < 256) {
        for (int k = 0; k < 128; ++k) {
            float c = tabC[n * 256 + k], s = tabS[n * 256 + k];
            acc += c * l1_re[k * 256 + ep] + s * l1_im[k * 256 + ep];
        }
    } else {
        int e = ep - 256;
        for (int k = 0; k < 128; ++k) {
            float c = tabC[n * 256 + k], s = tabS[n * 256 + k];
            acc += c * l1_im[k * 256 + e] - s * l1_re[k * 256 + e];
        }
    }
    Wa[(size_t)ep * 512 + n] = acc * inv;
}

// Wm[s][kk]: kk<256 -> coeff of Re bin kk, kk>=256 -> coeff of Im bin kk-256 (Im DC -> 0)
// irfft(ortho, 256 bins, n=512): x[n] = inv*(ReX0 + sum_{k>=1} 2(ReXk cos - ImXk sin))
__global__ __launch_bounds__(256) void wm_kernel(const float* __restrict__ lc_w,
                                                 const float* __restrict__ tabC, const float* __restrict__ tabS,
                                                 float* __restrict__ Wm)
{
    int s  = blockIdx.x;                       // 0..511
    int kk = blockIdx.y * 256 + threadIdx.x;   // 0..511
    const float inv = 0.04419417382415922f;
    float acc = 0.f;
    if (kk < 256) {
        int k = kk;
        for (int n = 0; n < 512; ++n)
            acc += tabC[n * 256 + k] * lc_w[s * 512 + n];
        acc *= (k == 0) ? inv : 2.f * inv;
    } else {
        int k = kk - 256;
        if (k == 0) acc = 0.f;
        else {
            for (int n = 0; n < 512; ++n)
                acc += tabS[n * 256 + k] * lc_w[s * 512 + n];
            acc *= -2.f * inv;
        }
    }
    Wm[(size_t)s * 512 + kk] = acc;
}

// pack [lb1_re | lb1_im] into one 512 bias vector
__global__ __launch_bounds__(256) void lbpack_kernel(const float* __restrict__ re, const float* __restrict__ im,
                                                     float* __restrict__ out)
{
    int i = threadIdx.x + blockIdx.x * 256;   // 0..511
    out[i] = (i < 256) ? re[i] : im[i - 256];
}

// ---------------- tiled GEMM: C[M,N] = A[M,K] @ W[N,K]^T + bias, opt relu ----------------
template <int ACT>
__global__ __launch_bounds__(256) void gemm_k(const float* __restrict__ A, const float* __restrict__ W,
                                              const float* __restrict__ bias, float* __restrict__ C,
                                              int M, int N, int K)
{
    __shared__ float As[64][17];
    __shared__ float Bs[64][17];
    const int tid = threadIdx.x;
    const int tx = tid & 15;          // n quad
    const int ty = tid >> 4;          // m quad
    const int m0 = blockIdx.y * 64;
    const int n0 = blockIdx.x * 64;
    const int lr = tid >> 2;          // 0..63
    const int lc = (tid & 3) << 2;    // 0,4,8,12
    const float* aptr = A + (size_t)(m0 + lr) * K + lc;
    const float* wptr = W + (size_t)(n0 + lr) * K + lc;
    float acc[4][4] = {};
    for (int k0 = 0; k0 < K; k0 += 16) {
        float4 av = *(const float4*)(aptr + k0);
        float4 wv = *(const float4*)(wptr + k0);
        As[lr][lc + 0] = av.x; As[lr][lc + 1] = av.y; As[lr][lc + 2] = av.z; As[lr][lc + 3] = av.w;
        Bs[lr][lc + 0] = wv.x; Bs[lr][lc + 1] = wv.y; Bs[lr][lc + 2] = wv.z; Bs[lr][lc + 3] = wv.w;
        __syncthreads();
#pragma unroll
        for (int kk = 0; kk < 16; ++kk) {
            float a[4], b[4];
#pragma unroll
            for (int i = 0; i < 4; ++i) a[i] = As[ty * 4 + i][kk];
#pragma unroll
            for (int j = 0; j < 4; ++j) b[j] = Bs[tx * 4 + j][kk];
#pragma unroll
            for (int i = 0; i < 4; ++i)
#pragma unroll
                for (int j = 0; j < 4; ++j)
                    acc[i][j] = fmaf(a[i], b[j], acc[i][j]);
        }
        __syncthreads();
    }
#pragma unroll
    for (int i = 0; i < 4; ++i) {
        int m = m0 + ty * 4 + i;
#pragma unroll
        for (int j = 0; j < 4; ++j) {
            int n = n0 + tx * 4 + j;
            float v = acc[i][j] + bias[n];
            if (ACT) v = fmaxf(v, 0.f);
            C[(size_t)m * N + n] = v;
        }
    }
}

// ---------------- TEL attention: one block per (batch, head) ----------------
__global__ __launch_bounds__(256) void attn_kernel(const float* __restrict__ qkv, float* __restrict__ out)
{
    const int b = blockIdx.x >> 3;
    const int h = blockIdx.x & 7;
    __shared__ float qs[32][65], ks[32][65], vs[32][65];
    __shared__ float ps[32][33];
    const int tid = threadIdx.x;
    for (int i = tid; i < 2048; i += 256) {
        int s = i >> 6, d = i & 63;
        size_t base = ((size_t)(b * 32 + s)) * 1536 + h * 64 + d;
        qs[s][d] = qkv[base];
        ks[s][d] = qkv[base + 512];
        vs[s][d] = qkv[base + 1024];
    }
    __syncthreads();
    for (int i = tid; i < 1024; i += 256) {
        int si = i >> 5, sj = i & 31;
        float acc = 0.f;
#pragma unroll 8
        for (int d = 0; d < 64; ++d) acc += qs[si][d] * ks[sj][d];
        ps[si][sj] = acc * 0.125f;   // 1/sqrt(64)
    }
    __syncthreads();
    if (tid < 32) {
        float mx = -1e30f;
        for (int j = 0; j < 32; ++j) mx = fmaxf(mx, ps[tid][j]);
        float sum = 0.f;
        for (int j = 0; j < 32; ++j) { float e = __expf(ps[tid][j] - mx); ps[tid][j] = e; sum += e; }
        float inv = 1.f / sum;
        for (int j = 0; j < 32; ++j) ps[tid][j] *= inv;
    }
    __syncthreads();
    for (int i = tid; i < 2048; i += 256) {
        int s = i >> 6, d = i & 63;
        float acc = 0.f;
#pragma unroll 8
        for (int k = 0; k < 32; ++k) acc += ps[s][k] * vs[k][d];
        out[((size_t)(b * 32 + s)) * 512 + h * 64 + d] = acc;
    }
}

// ---------------- complex self-attention on low, in-place LL += cattn(LL) ----------------
// LL[m, 0:256]=re, LL[m,256:512]=im ; one block per batch (32 rows = channels)
__global__ __launch_bounds__(256) void cattn_kernel(float* __restrict__ LL)
{
    const int b = blockIdx.x;
    const int tid = threadIdx.x;
    __shared__ float Pr[32][33], Pi[32][33];
    float* base = LL + (size_t)b * 32 * 512;
    // scores: 4 (ci,ck) pairs per thread, same ci; scale 1/sqrt(EMB)=1/16
    {
        const int ci = tid >> 3;
        const int ck0 = (tid & 7) * 4;
        const float* xrow = base + (size_t)ci * 512;
        const float* kp0 = base + (size_t)(ck0 + 0) * 512;
        const float* kp1 = base + (size_t)(ck0 + 1) * 512;
        const float* kp2 = base + (size_t)(ck0 + 2) * 512;
        const float* kp3 = base + (size_t)(ck0 + 3) * 512;
        float a0 = 0, a1 = 0, a2 = 0, a3 = 0, b0 = 0, b1 = 0, b2 = 0, b3 = 0;
        for (int e = 0; e < 256; ++e) {
            float xr = xrow[e], xi = xrow[256 + e];
            float yr, yi;
            yr = kp0[e]; yi = kp0[256 + e]; a0 += xr * yr - xi * yi; b0 += xr * yi + xi * yr;
            yr = kp1[e]; yi = kp1[256 + e]; a1 += xr * yr - xi * yi; b1 += xr * yi + xi * yr;
            yr = kp2[e]; yi = kp2[256 + e]; a2 += xr * yr - xi * yi; b2 += xr * yi + xi * yr;
            yr = kp3[e]; yi = kp3[256 + e]; a3 += xr * yr - xi * yi; b3 += xr * yi + xi * yr;
        }
        Pr[ci][ck0 + 0] = a0 * 0.0625f; Pr[ci][ck0 + 1] = a1 * 0.0625f;
        Pr[ci][ck0 + 2] = a2 * 0.0625f; Pr[ci][ck0 + 3] = a3 * 0.0625f;
        Pi[ci][ck0 + 0] = b0 * 0.0625f; Pi[ci][ck0 + 1] = b1 * 0.0625f;
        Pi[ci][ck0 + 2] = b2 * 0.0625f; Pi[ci][ck0 + 3] = b3 * 0.0625f;
    }
    __syncthreads();
    if (tid < 64) {   // 32 rows re + 32 rows im, softmax over k
        int r = tid & 31;
        float (*P)[33] = (tid < 32) ? Pr : Pi;
        float mx = -1e30f;
        for (int j = 0; j < 32; ++j) mx = fmaxf(mx, P[r][j]);
        float s = 0.f;
        for (int j = 0; j < 32; ++j) { float e = __expf(P[r][j] - mx); P[r][j] = e; s += e; }
        float inv = 1.f / s;
        for (int j = 0; j < 32; ++j) P[r][j] *= inv;
    }
    __syncthreads();
    // out: thread tid handles embed column e=tid for all 32 rows
    float accr[32], acci[32];
#pragma unroll
    for (int t = 0; t < 32; ++t) { accr[t] = 0.f; acci[t] = 0.f; }
    for (int k = 0; k < 32; ++k) {
        float yr = base[(size_t)k * 512 + tid];
        float yi = base[(size_t)k * 512 + 256 + tid];
#pragma unroll
        for (int t = 0; t < 32; ++t) {
            float pr = Pr[t][k], pi = Pi[t][k];
            accr[t] += pr * yr - pi * yi;
            acci[t] += pr * yi + pi * yr;
        }
    }
    __syncthreads();   // all LDS-phase reads done; each thread's global reads precede its writes
#pragma unroll
    for (int t = 0; t < 32; ++t) {
        float* p = base + (size_t)t * 512 + tid;
        p[0]   += accr[t];
        p[256] += acci[t];
    }
}

// ---------------- residual add + LayerNorm over last dim (512) ----------------
__global__ __launch_bounds__(256) void add_ln_kernel(const float* __restrict__ resid, const float* __restrict__ y,
                                                     const float* __restrict__ w, const float* __restrict__ b,
                                                     float* __restrict__ out)
{
    const int row = blockIdx.x;
    const int tid = threadIdx.x;
    const size_t base = (size_t)row * 512;
    float v0 = resid[base + tid] + y[base + tid];
    float v1 = resid[base + 256 + tid] + y[base + 256 + tid];
    float s = v0 + v1, q = v0 * v0 + v1 * v1;
    for (int off = 32; off; off >>= 1) { s += __shfl_down(s, off); q += __shfl_down(q, off); }
    __shared__ float sw[4], qw[4], ms, is;
    int wid = tid >> 6, lane = tid & 63;
    if (lane == 0) { sw[wid] = s; qw[wid] = q; }
    __syncthreads();
    if (tid == 0) {
        float S = sw[0] + sw[1] + sw[2] + sw[3];
        float Q = qw[0] + qw[1] + qw[2] + qw[3];
        float m = S * (1.f / 512.f);
        ms = m;
        is = rsqrtf(Q * (1.f / 512.f) - m * m + 1e-5f);
    }
    __syncthreads();
    float m = ms, inv = is;
    out[base + tid]       = (v0 - m) * inv * w[tid] + b[tid];
    out[base + 256 + tid] = (v1 - m) * inv * w[256 + tid] + b[256 + tid];
}

// ---------------- relu + LayerNorm over (C,S)=16384 per batch, per-elem affine ----------------
__global__ __launch_bounds__(256) void relu_bln_kernel(const float* __restrict__ xin,
                                                       const float* __restrict__ w, const float* __restrict__ b,
                                                       float* __restrict__ out)
{
    const int bb = blockIdx.x;
    const int tid = threadIdx.x;
    const float* xp = xin + (size_t)bb * 16384;
    float s = 0.f, q = 0.f;
    for (int i = tid; i < 16384; i += 256) { float v = fmaxf(xp[i], 0.f); s += v; q += v * v; }
    for (int off = 32; off; off >>= 1) { s += __shfl_down(s, off); q += __shfl_down(q, off); }
    __shared__ float sw[4], qw[4], ms, is;
    int wid = tid >> 6, lane = tid & 63;
    if (lane == 0) { sw[wid] = s; qw[wid] = q; }
    __syncthreads();
    if (tid == 0) {
        float S = sw[0] + sw[1] + sw[2] + sw[3];
        float Q = qw[0] + qw[1] + qw[2] + qw[3];
        float m = S * (1.f / 16384.f);
        ms = m;
        is = rsqrtf(Q * (1.f / 16384.f) - m * m + 1e-5f);
    }
    __syncthreads();
    float m = ms, inv = is;
    float* op = out + (size_t)bb * 16384;
    for (int i = tid; i < 16384; i += 256) {
        float v = fmaxf(xp[i], 0.f);
        op[i] = (v - m) * inv * w[i] + b[i];   // in-place safe: same idx set per thread
    }
}

__global__ __launch_bounds__(256) void add_f32_kernel(const float* __restrict__ a, const float* __restrict__ bsrc,
                                                      float* __restrict__ o, int n)
{
    for (int i = blockIdx.x * 256 + threadIdx.x; i < n; i += gridDim.x * 256)
        o[i] = a[i] + bsrc[i];
}

extern "C" void kernel_launch(void* const* d_in, const int* in_sizes, int n_in,
                              void* d_out, int out_size, void* d_ws, size_t ws_size,
                              hipStream_t stream)
{
    (void)in_sizes; (void)n_in; (void)out_size; (void)ws_size;
    const float* x        = (const float*)d_in[0];
    const float* t_in_w   = (const float*)d_in[1];
    const float* t_in_b   = (const float*)d_in[2];
    const float* t_out_w  = (const float*)d_in[3];
    const float* t_out_b  = (const float*)d_in[4];
    const float* t_ln1_w  = (const float*)d_in[5];
    const float* t_ln1_b  = (const float*)d_in[6];
    const float* t_lin1_w = (const float*)d_in[7];
    const float* t_lin1_b = (const float*)d_in[8];
    const float* t_lin2_w = (const float*)d_in[9];
    const float* t_lin2_b = (const float*)d_in[10];
    const float* t_ln2_w  = (const float*)d_in[11];
    const float* t_ln2_b  = (const float*)d_in[12];
    const float* r_in_w   = (const float*)d_in[13];
    const float* r_in_b   = (const float*)d_in[14];
    const float* r_out_w  = (const float*)d_in[15];
    const float* r_out_b  = (const float*)d_in[16];
    const float* r_ln1_w  = (const float*)d_in[17];
    const float* r_ln1_b  = (const float*)d_in[18];
    const float* r_lin1_w = (const float*)d_in[19];
    const float* r_lin1_b = (const float*)d_in[20];
    const float* r_lin2_w = (const float*)d_in[21];
    const float* r_lin2_b = (const float*)d_in[22];
    const float* r_ln2_w  = (const float*)d_in[23];
    const float* r_ln2_b  = (const float*)d_in[24];
    const float* lc_w     = (const float*)d_in[25];
    const float* lc_b     = (const float*)d_in[26];
    const float* up1_w    = (const float*)d_in[27];
    const float* up1_b    = (const float*)d_in[28];
    const float* up2_w    = (const float*)d_in[29];
    const float* up2_b    = (const float*)d_in[30];
    const float* n1_w     = (const float*)d_in[31];
    const float* n1_b     = (const float*)d_in[32];
    const float* n2_w     = (const float*)d_in[33];
    const float* n2_b     = (const float*)d_in[34];
    const float* l1_re    = (const float*)d_in[35];
    const float* l1_im    = (const float*)d_in[36];
    // d_in[37..38]: h1_re/h1_im (dead), d_in[41..42]: hb1 (dead)
    const float* lb1_re   = (const float*)d_in[39];
    const float* lb1_im   = (const float*)d_in[40];

    float* outp = (float*)d_out;

    // workspace arenas (floats)
    float* WS   = (float*)d_ws;
    float* tabC = WS + 0;          // 131072
    float* tabS = WS + 131072;     // 131072
    float* Wa   = WS + 262144;     // 262144
    float* Wm   = WS + 524288;     // 262144
    float* LB   = WS + 786432;     // 512
    float* BIG  = WS + 802816;     // 8388608 (qkv / f1)
    float* Aa   = WS + 9191424;    // 2097152 (attn_out / u1)
    float* Bb   = WS + 11288576;   // 2097152 (o / f2)
    float* Cc   = WS + 13385728;   // 2097152 (x1)
    float* Ee   = WS + 15482880;   // 2097152 (x2 -> df)
    float* LLp  = WS + 17580032;   // 2097152 (low re||im -> x2r -> rf)
    float* FAp  = WS + 19677184;   // 2097152 (fa)
    // end: 21774336 floats = 87.1 MB

    dim3 blk(256);

    // ---- prep ----
    tab_kernel<<<dim3(512), blk, 0, stream>>>(tabC, tabS);
    wa_kernel<<<dim3(512, 2), blk, 0, stream>>>(l1_re, l1_im, tabC, tabS, Wa);
    wm_kernel<<<dim3(512, 2), blk, 0, stream>>>(lc_w, tabC, tabS, Wm);
    lbpack_kernel<<<dim3(2), blk, 0, stream>>>(lb1_re, lb1_im, LB);

    // ---- output 1: down_x = x ----
    hipMemcpyAsync(outp + NOUT, x, (size_t)NOUT * sizeof(float), hipMemcpyDeviceToDevice, stream);

    // ---- t-TEL on x ----
    gemm_k<0><<<dim3(24, 64), blk, 0, stream>>>(x, t_in_w, t_in_b, BIG, NROW, 1536, 512);
    attn_kernel<<<dim3(1024), blk, 0, stream>>>(BIG, Aa);
    gemm_k<0><<<dim3(8, 64), blk, 0, stream>>>(Aa, t_out_w, t_out_b, Bb, NROW, 512, 512);
    add_ln_kernel<<<dim3(4096), blk, 0, stream>>>(x, Bb, t_ln1_w, t_ln1_b, Cc);                 // x1
    gemm_k<1><<<dim3(32, 64), blk, 0, stream>>>(Cc, t_lin1_w, t_lin1_b, BIG, NROW, 2048, 512);
    gemm_k<0><<<dim3(8, 64), blk, 0, stream>>>(BIG, t_lin2_w, t_lin2_b, Bb, NROW, 512, 2048);
    add_ln_kernel<<<dim3(4096), blk, 0, stream>>>(Cc, Bb, t_ln2_w, t_ln2_b, Ee);                // x2
    relu_bln_kernel<<<dim3(128), blk, 0, stream>>>(Ee, n1_w, n1_b, Ee);                         // df (in-place)

    // ---- freq branch ----
    gemm_k<1><<<dim3(8, 64), blk, 0, stream>>>(x, Wa, LB, LLp, NROW, 512, 512);                 // crelu(low)
    cattn_kernel<<<dim3(128), blk, 0, stream>>>(LLp);                                           // low += cattn(low)
    gemm_k<0><<<dim3(8, 64), blk, 0, stream>>>(LLp, Wm, lc_b, FAp, NROW, 512, 512);             // fa
    hipMemcpyAsync(outp + 2 * NOUT, FAp, (size_t)NOUT * sizeof(float), hipMemcpyDeviceToDevice, stream); // output 2
    gemm_k<0><<<dim3(8, 64), blk, 0, stream>>>(FAp, up1_w, up1_b, Aa, NROW, 512, 512);
    gemm_k<0><<<dim3(8, 64), blk, 0, stream>>>(Aa, up2_w, up2_b, outp + 3 * NOUT, NROW, 512, 512); // output 3

    // ---- r-TEL on fa ----
    gemm_k<0><<<dim3(24, 64), blk, 0, stream>>>(FAp, r_in_w, r_in_b, BIG, NROW, 1536, 512);
    attn_kernel<<<dim3(1024), blk, 0, stream>>>(BIG, Aa);
    gemm_k<0><<<dim3(8, 64), blk, 0, stream>>>(Aa, r_out_w, r_out_b, Bb, NROW, 512, 512);
    add_ln_kernel<<<dim3(4096), blk, 0, stream>>>(FAp, Bb, r_ln1_w, r_ln1_b, Cc);               // x1r
    gemm_k<1><<<dim3(32, 64), blk, 0, stream>>>(Cc, r_lin1_w, r_lin1_b, BIG, NROW, 2048, 512);
    gemm_k<0><<<dim3(8, 64), blk, 0, stream>>>(BIG, r_lin2_w, r_lin2_b, Bb, NROW, 512, 2048);
    add_ln_kernel<<<dim3(4096), blk, 0, stream>>>(Cc, Bb, r_ln2_w, r_ln2_b, LLp);               // x2r
    relu_bln_kernel<<<dim3(128), blk, 0, stream>>>(LLp, n2_w, n2_b, LLp);                       // rf (in-place)

    // ---- output 0: res = df + rf ----
    add_f32_kernel<<<dim3(2048), blk, 0, stream>>>(Ee, LLp, outp, NOUT);
}

// Round 3
// 872.742 us; speedup vs baseline: 2.0697x; 2.0697x over previous
//
#include <hip/hip_runtime.h>
#include <math.h>

// NoiScaleModule: B=128, C=32(seq), S=512(d_model), EMB=256, NHEAD=8, DFF=2048
// All tensors FLOAT32. Outputs concat flat: res[2M], down_x[2M], fa[2M], up[2M]
//
// Simplifications:
//  - 'high' freq branch dead (xcat == low); h1/hb1 unused.
//  - rfft folded into low-projection (Wa); irfft+linear_change folded (Wm).
//  - 10 big GEMMs on bf16 MFMA (16x16x32, 128x128 tile, global_load_lds);
//    r-qkv uses hi/lo bf16 split (3-pass) to protect the near-one-hot r-attention softmax;
//    freq branch (Wa/cattn/Wm) stays f32 for exactness of fa and cattn scores.

#define NROW 4096
#define NOUT 2097152

typedef __attribute__((ext_vector_type(8))) short short8;
typedef __attribute__((ext_vector_type(4))) float floatx4;

__device__ __forceinline__ unsigned short f2bf(float f) {
    union { float f; unsigned u; } v; v.f = f;
    return (unsigned short)((v.u + 0x7fffu + ((v.u >> 16) & 1u)) >> 16);
}
__device__ __forceinline__ float bf2f(unsigned short h) {
    union { unsigned u; float f; } v; v.u = ((unsigned)h) << 16;
    return v.f;
}
__device__ __forceinline__ float ldv(const float* p, size_t i) { return p[i]; }
__device__ __forceinline__ float ldv(const unsigned short* p, size_t i) { return bf2f(p[i]); }

__device__ __forceinline__ void gload16(const unsigned short* g, unsigned short* l) {
    __builtin_amdgcn_global_load_lds((const __attribute__((address_space(1))) void*)g,
                                     (__attribute__((address_space(3))) void*)l, 16, 0, 0);
}

// ---------------- prep: cos/sin tables tab[n][k], n<512, k<256 ----------------
__global__ __launch_bounds__(256) void tab_kernel(float* __restrict__ tabC, float* __restrict__ tabS)
{
    int n = blockIdx.x, k = threadIdx.x;
    int m = (n * k) & 511;
    float th = (float)m * 0.01227184630308513f;  // 2*pi/512
    float s, c; sincosf(th, &s, &c);
    tabC[n * 256 + k] = c;
    tabS[n * 256 + k] = s;
}

__global__ __launch_bounds__(256) void wa_kernel(const float* __restrict__ l1_re, const float* __restrict__ l1_im,
                                                 const float* __restrict__ tabC, const float* __restrict__ tabS,
                                                 float* __restrict__ Wa)
{
    int n  = blockIdx.x;
    int ep = blockIdx.y * 256 + threadIdx.x;
    const float inv = 0.04419417382415922f;  // 1/sqrt(512)
    float acc = 0.f;
    if (ep < 256) {
        for (int k = 0; k < 128; ++k) {
            float c = tabC[n * 256 + k], s = tabS[n * 256 + k];
            acc += c * l1_re[k * 256 + ep] + s * l1_im[k * 256 + ep];
        }
    } else {
        int e = ep - 256;
        for (int k = 0; k < 128; ++k) {
            float c = tabC[n * 256 + k], s = tabS[n * 256 + k];
            acc += c * l1_im[k * 256 + e] - s * l1_re[k * 256 + e];
        }
    }
    Wa[(size_t)ep * 512 + n] = acc * inv;
}

__global__ __launch_bounds__(256) void wm_kernel(const float* __restrict__ lc_w,
                                                 const float* __restrict__ tabC, const float* __restrict__ tabS,
                                                 float* __restrict__ Wm)
{
    int s  = blockIdx.x;
    int kk = blockIdx.y * 256 + threadIdx.x;
    const float inv = 0.04419417382415922f;
    float acc = 0.f;
    if (kk < 256) {
        int k = kk;
        for (int n = 0; n < 512; ++n) acc += tabC[n * 256 + k] * lc_w[s * 512 + n];
        acc *= (k == 0) ? inv : 2.f * inv;
    } else {
        int k = kk - 256;
        if (k == 0) acc = 0.f;
        else {
            for (int n = 0; n < 512; ++n) acc += tabS[n * 256 + k] * lc_w[s * 512 + n];
            acc *= -2.f * inv;
        }
    }
    Wm[(size_t)s * 512 + kk] = acc;
}

// LB[0:512] = [lb1_re|lb1_im]; LB[512:1024] = 0 (zero bias for accumulate passes)
__global__ __launch_bounds__(256) void lbpack_kernel(const float* __restrict__ re, const float* __restrict__ im,
                                                     float* __restrict__ out)
{
    int i = threadIdx.x + blockIdx.x * 256;  // 0..1023
    out[i] = (i < 256) ? re[i] : (i < 512 ? im[i - 256] : 0.f);
}

// convert all 10 weight matrices to bf16 into one arena
__global__ __launch_bounds__(256) void wcvt_kernel(
    const float* s0, const float* s1, const float* s2, const float* s3, const float* s4,
    const float* s5, const float* s6, const float* s7, const float* s8, const float* s9,
    unsigned short* __restrict__ o)
{
    int i = blockIdx.x * 256 + threadIdx.x;
    if (i >= 6815744) return;
    const float* s; int off;
    if (i < 3145728) {
        if (i < 1048576) { if (i < 786432) { s = s0; off = 0; } else { s = s1; off = 786432; } }
        else             { if (i < 2097152) { s = s2; off = 1048576; } else { s = s3; off = 2097152; } }
    } else {
        if (i < 5242880) {
            if (i < 3932160) { s = s4; off = 3145728; }
            else if (i < 4194304) { s = s5; off = 3932160; }
            else { s = s6; off = 4194304; }
        } else {
            if (i < 6291456) { s = s7; off = 5242880; }
            else if (i < 6553600) { s = s8; off = 6291456; }
            else { s = s9; off = 6553600; }
        }
    }
    o[i] = f2bf(s[i - off]);
}

__global__ __launch_bounds__(256) void cvt_b_kernel(const float* __restrict__ a, unsigned short* __restrict__ o, int n)
{
    for (int i = blockIdx.x * 256 + threadIdx.x; i < n; i += gridDim.x * 256) o[i] = f2bf(a[i]);
}
__global__ __launch_bounds__(256) void cvt_hilo_kernel(const float* __restrict__ a, unsigned short* __restrict__ hi,
                                                       unsigned short* __restrict__ lo, int n)
{
    for (int i = blockIdx.x * 256 + threadIdx.x; i < n; i += gridDim.x * 256) {
        unsigned short h = f2bf(a[i]);
        hi[i] = h;
        lo[i] = f2bf(a[i] - bf2f(h));
    }
}
__global__ __launch_bounds__(256) void cvt_lo_kernel(const float* __restrict__ a, const unsigned short* __restrict__ hi,
                                                     unsigned short* __restrict__ lo, int n)
{
    for (int i = blockIdx.x * 256 + threadIdx.x; i < n; i += gridDim.x * 256)
        lo[i] = f2bf(a[i] - bf2f(hi[i]));
}

// ---------------- MFMA GEMM: C[M,N] = A[M,K](bf16) @ W[N,K](bf16)^T + bias ----------------
// 128x128 tile, BK=32, 4 waves (2x2), each wave 64x64 via 4x4 mfma_16x16x32_bf16.
template <int ACT, int WF, int WBF, int ACCUM>
__global__ __launch_bounds__(256) void gemm_mfma(
    const unsigned short* __restrict__ A, const unsigned short* __restrict__ W,
    const float* __restrict__ bias, float* __restrict__ Cf, unsigned short* __restrict__ Cb,
    int N, int K)
{
    __shared__ unsigned short As[128 * 32];
    __shared__ unsigned short Bs[128 * 32];
    const int tid = threadIdx.x;
    const int wave = tid >> 6, lane = tid & 63;
    const int m0 = blockIdx.y * 128, n0 = blockIdx.x * 128;
    // staging: wave w chunk c covers tile rows [w*32+c*16, +16); lane l -> row +(l>>2), col (l&3)*8
    const int sr = lane >> 2, sc = (lane & 3) * 8;
    const unsigned short* aS0 = A + (size_t)(m0 + wave * 32 + sr) * K + sc;
    const unsigned short* aS1 = aS0 + (size_t)16 * K;
    const unsigned short* wS0 = W + (size_t)(n0 + wave * 32 + sr) * K + sc;
    const unsigned short* wS1 = wS0 + (size_t)16 * K;
    unsigned short* aD0 = &As[(wave * 32) * 32];
    unsigned short* aD1 = &As[(wave * 32 + 16) * 32];
    unsigned short* bD0 = &Bs[(wave * 32) * 32];
    unsigned short* bD1 = &Bs[(wave * 32 + 16) * 32];
    const int wm = (wave >> 1) * 64, wn = (wave & 1) * 64;
    const int fr = lane & 15, fko = (lane >> 4) * 8;

    floatx4 acc[4][4];
#pragma unroll
    for (int i = 0; i < 4; ++i)
#pragma unroll
        for (int j = 0; j < 4; ++j) acc[i][j] = (floatx4){0.f, 0.f, 0.f, 0.f};

    for (int k0 = 0; k0 < K; k0 += 32) {
        gload16(aS0 + k0, aD0);
        gload16(aS1 + k0, aD1);
        gload16(wS0 + k0, bD0);
        gload16(wS1 + k0, bD1);
        __syncthreads();
        short8 af[4], bfr[4];
#pragma unroll
        for (int i = 0; i < 4; ++i) af[i] = *(const short8*)&As[(wm + i * 16 + fr) * 32 + fko];
#pragma unroll
        for (int j = 0; j < 4; ++j) bfr[j] = *(const short8*)&Bs[(wn + j * 16 + fr) * 32 + fko];
#pragma unroll
        for (int i = 0; i < 4; ++i)
#pragma unroll
            for (int j = 0; j < 4; ++j)
                acc[i][j] = __builtin_amdgcn_mfma_f32_16x16x32_bf16(af[i], bfr[j], acc[i][j], 0, 0, 0);
        __syncthreads();
    }
    const int r0 = m0 + wm + (lane >> 4) * 4;
#pragma unroll
    for (int i = 0; i < 4; ++i) {
#pragma unroll
        for (int j = 0; j < 4; ++j) {
            int n = n0 + wn + j * 16 + fr;
            float bv = bias[n];
#pragma unroll
            for (int r = 0; r < 4; ++r) {
                int m = r0 + i * 16 + r;
                size_t idx = (size_t)m * N + n;
                float v = acc[i][j][r] + bv;
                if (ACT) v = fmaxf(v, 0.f);
                if (ACCUM) v += Cf[idx];
                if (WF) Cf[idx] = v;
                if (WBF) Cb[idx] = f2bf(v);
            }
        }
    }
}

// ---------------- f32 tiled GEMM (freq branch only) ----------------
template <int ACT>
__global__ __launch_bounds__(256) void gemm_k(const float* __restrict__ A, const float* __restrict__ W,
                                              const float* __restrict__ bias, float* __restrict__ C,
                                              int M, int N, int K)
{
    __shared__ float As[64][17];
    __shared__ float Bs[64][17];
    const int tid = threadIdx.x;
    const int tx = tid & 15, ty = tid >> 4;
    const int m0 = blockIdx.y * 64, n0 = blockIdx.x * 64;
    const int lr = tid >> 2, lc = (tid & 3) << 2;
    const float* aptr = A + (size_t)(m0 + lr) * K + lc;
    const float* wptr = W + (size_t)(n0 + lr) * K + lc;
    float acc[4][4] = {};
    for (int k0 = 0; k0 < K; k0 += 16) {
        float4 av = *(const float4*)(aptr + k0);
        float4 wv = *(const float4*)(wptr + k0);
        As[lr][lc + 0] = av.x; As[lr][lc + 1] = av.y; As[lr][lc + 2] = av.z; As[lr][lc + 3] = av.w;
        Bs[lr][lc + 0] = wv.x; Bs[lr][lc + 1] = wv.y; Bs[lr][lc + 2] = wv.z; Bs[lr][lc + 3] = wv.w;
        __syncthreads();
#pragma unroll
        for (int kk = 0; kk < 16; ++kk) {
            float a[4], b[4];
#pragma unroll
            for (int i = 0; i < 4; ++i) a[i] = As[ty * 4 + i][kk];
#pragma unroll
            for (int j = 0; j < 4; ++j) b[j] = Bs[tx * 4 + j][kk];
#pragma unroll
            for (int i = 0; i < 4; ++i)
#pragma unroll
                for (int j = 0; j < 4; ++j) acc[i][j] = fmaf(a[i], b[j], acc[i][j]);
        }
        __syncthreads();
    }
#pragma unroll
    for (int i = 0; i < 4; ++i) {
        int m = m0 + ty * 4 + i;
#pragma unroll
        for (int j = 0; j < 4; ++j) {
            int n = n0 + tx * 4 + j;
            float v = acc[i][j] + bias[n];
            if (ACT) v = fmaxf(v, 0.f);
            C[(size_t)m * N + n] = v;
        }
    }
}

// ---------------- TEL attention: one block per (batch, head); bf16 out ----------------
template <typename T>
__global__ __launch_bounds__(256) void attn_kernel(const T* __restrict__ qkv, unsigned short* __restrict__ outb)
{
    const int b = blockIdx.x >> 3;
    const int h = blockIdx.x & 7;
    __shared__ float qs[32][65], ks[32][65], vs[32][65];
    __shared__ float ps[32][33];
    const int tid = threadIdx.x;
    for (int i = tid; i < 2048; i += 256) {
        int s = i >> 6, d = i & 63;
        size_t base = ((size_t)(b * 32 + s)) * 1536 + h * 64 + d;
        qs[s][d] = ldv(qkv, base);
        ks[s][d] = ldv(qkv, base + 512);
        vs[s][d] = ldv(qkv, base + 1024);
    }
    __syncthreads();
    for (int i = tid; i < 1024; i += 256) {
        int si = i >> 5, sj = i & 31;
        float acc = 0.f;
#pragma unroll 8
        for (int d = 0; d < 64; ++d) acc += qs[si][d] * ks[sj][d];
        ps[si][sj] = acc * 0.125f;
    }
    __syncthreads();
    if (tid < 32) {
        float mx = -1e30f;
        for (int j = 0; j < 32; ++j) mx = fmaxf(mx, ps[tid][j]);
        float sum = 0.f;
        for (int j = 0; j < 32; ++j) { float e = __expf(ps[tid][j] - mx); ps[tid][j] = e; sum += e; }
        float inv = 1.f / sum;
        for (int j = 0; j < 32; ++j) ps[tid][j] *= inv;
    }
    __syncthreads();
    for (int i = tid; i < 2048; i += 256) {
        int s = i >> 6, d = i & 63;
        float acc = 0.f;
#pragma unroll 8
        for (int k = 0; k < 32; ++k) acc += ps[s][k] * vs[k][d];
        outb[((size_t)(b * 32 + s)) * 512 + h * 64 + d] = f2bf(acc);
    }
}

// ---------------- complex self-attention, in-place LL += cattn(LL) (f32) ----------------
__global__ __launch_bounds__(256) void cattn_kernel(float* __restrict__ LL)
{
    const int b = blockIdx.x;
    const int tid = threadIdx.x;
    __shared__ float Pr[32][33], Pi[32][33];
    float* base = LL + (size_t)b * 32 * 512;
    {
        const int ci = tid >> 3;
        const int ck0 = (tid & 7) * 4;
        const float* xrow = base + (size_t)ci * 512;
        const float* kp0 = base + (size_t)(ck0 + 0) * 512;
        const float* kp1 = base + (size_t)(ck0 + 1) * 512;
        const float* kp2 = base + (size_t)(ck0 + 2) * 512;
        const float* kp3 = base + (size_t)(ck0 + 3) * 512;
        float a0 = 0, a1 = 0, a2 = 0, a3 = 0, b0 = 0, b1 = 0, b2 = 0, b3 = 0;
        for (int e = 0; e < 256; ++e) {
            float xr = xrow[e], xi = xrow[256 + e];
            float yr, yi;
            yr = kp0[e]; yi = kp0[256 + e]; a0 += xr * yr - xi * yi; b0 += xr * yi + xi * yr;
            yr = kp1[e]; yi = kp1[256 + e]; a1 += xr * yr - xi * yi; b1 += xr * yi + xi * yr;
            yr = kp2[e]; yi = kp2[256 + e]; a2 += xr * yr - xi * yi; b2 += xr * yi + xi * yr;
            yr = kp3[e]; yi = kp3[256 + e]; a3 += xr * yr - xi * yi; b3 += xr * yi + xi * yr;
        }
        Pr[ci][ck0 + 0] = a0 * 0.0625f; Pr[ci][ck0 + 1] = a1 * 0.0625f;
        Pr[ci][ck0 + 2] = a2 * 0.0625f; Pr[ci][ck0 + 3] = a3 * 0.0625f;
        Pi[ci][ck0 + 0] = b0 * 0.0625f; Pi[ci][ck0 + 1] = b1 * 0.0625f;
        Pi[ci][ck0 + 2] = b2 * 0.0625f; Pi[ci][ck0 + 3] = b3 * 0.0625f;
    }
    __syncthreads();
    if (tid < 64) {
        int r = tid & 31;
        float (*P)[33] = (tid < 32) ? Pr : Pi;
        float mx = -1e30f;
        for (int j = 0; j < 32; ++j) mx = fmaxf(mx, P[r][j]);
        float s = 0.f;
        for (int j = 0; j < 32; ++j) { float e = __expf(P[r][j] - mx); P[r][j] = e; s += e; }
        float inv = 1.f / s;
        for (int j = 0; j < 32; ++j) P[r][j] *= inv;
    }
    __syncthreads();
    float accr[32], acci[32];
#pragma unroll
    for (int t = 0; t < 32; ++t) { accr[t] = 0.f; acci[t] = 0.f; }
    for (int k = 0; k < 32; ++k) {
        float yr = base[(size_t)k * 512 + tid];
        float yi = base[(size_t)k * 512 + 256 + tid];
#pragma unroll
        for (int t = 0; t < 32; ++t) {
            float pr = Pr[t][k], pi = Pi[t][k];
            accr[t] += pr * yr - pi * yi;
            acci[t] += pr * yi + pi * yr;
        }
    }
    __syncthreads();
#pragma unroll
    for (int t = 0; t < 32; ++t) {
        float* p = base + (size_t)t * 512 + tid;
        p[0]   += accr[t];
        p[256] += acci[t];
    }
}

// ---------------- residual add + LayerNorm over last dim (512), optional bf16 copy ----------------
template <int WBF>
__global__ __launch_bounds__(256) void add_ln_kernel(const float* __restrict__ resid, const float* __restrict__ y,
                                                     const float* __restrict__ w, const float* __restrict__ b,
                                                     float* __restrict__ outf, unsigned short* __restrict__ outb)
{
    const int row = blockIdx.x;
    const int tid = threadIdx.x;
    const size_t base = (size_t)row * 512;
    float v0 = resid[base + tid] + y[base + tid];
    float v1 = resid[base + 256 + tid] + y[base + 256 + tid];
    float s = v0 + v1, q = v0 * v0 + v1 * v1;
    for (int off = 32; off; off >>= 1) { s += __shfl_down(s, off); q += __shfl_down(q, off); }
    __shared__ float sw[4], qw[4], ms, is;
    int wid = tid >> 6, lane = tid & 63;
    if (lane == 0) { sw[wid] = s; qw[wid] = q; }
    __syncthreads();
    if (tid == 0) {
        float S = sw[0] + sw[1] + sw[2] + sw[3];
        float Q = qw[0] + qw[1] + qw[2] + qw[3];
        float m = S * (1.f / 512.f);
        ms = m;
        is = rsqrtf(Q * (1.f / 512.f) - m * m + 1e-5f);
    }
    __syncthreads();
    float m = ms, inv = is;
    float o0 = (v0 - m) * inv * w[tid] + b[tid];
    float o1 = (v1 - m) * inv * w[256 + tid] + b[256 + tid];
    outf[base + tid] = o0;
    outf[base + 256 + tid] = o1;
    if (WBF) { outb[base + tid] = f2bf(o0); outb[base + 256 + tid] = f2bf(o1); }
}

// ---------------- relu + LayerNorm over (C,S)=16384 per batch ----------------
__global__ __launch_bounds__(256) void relu_bln_kernel(const float* __restrict__ xin,
                                                       const float* __restrict__ w, const float* __restrict__ b,
                                                       float* __restrict__ out)
{
    const int bb = blockIdx.x;
    const int tid = threadIdx.x;
    const float* xp = xin + (size_t)bb * 16384;
    float s = 0.f, q = 0.f;
    for (int i = tid; i < 16384; i += 256) { float v = fmaxf(xp[i], 0.f); s += v; q += v * v; }
    for (int off = 32; off; off >>= 1) { s += __shfl_down(s, off); q += __shfl_down(q, off); }
    __shared__ float sw[4], qw[4], ms, is;
    int wid = tid >> 6, lane = tid & 63;
    if (lane == 0) { sw[wid] = s; qw[wid] = q; }
    __syncthreads();
    if (tid == 0) {
        float S = sw[0] + sw[1] + sw[2] + sw[3];
        float Q = qw[0] + qw[1] + qw[2] + qw[3];
        float m = S * (1.f / 16384.f);
        ms = m;
        is = rsqrtf(Q * (1.f / 16384.f) - m * m + 1e-5f);
    }
    __syncthreads();
    float m = ms, inv = is;
    float* op = out + (size_t)bb * 16384;
    for (int i = tid; i < 16384; i += 256) {
        float v = fmaxf(xp[i], 0.f);
        op[i] = (v - m) * inv * w[i] + b[i];
    }
}

__global__ __launch_bounds__(256) void add_f32_kernel(const float* __restrict__ a, const float* __restrict__ bsrc,
                                                      float* __restrict__ o, int n)
{
    for (int i = blockIdx.x * 256 + threadIdx.x; i < n; i += gridDim.x * 256) o[i] = a[i] + bsrc[i];
}

extern "C" void kernel_launch(void* const* d_in, const int* in_sizes, int n_in,
                              void* d_out, int out_size, void* d_ws, size_t ws_size,
                              hipStream_t stream)
{
    (void)in_sizes; (void)n_in; (void)out_size; (void)ws_size;
    const float* x        = (const float*)d_in[0];
    const float* t_in_w   = (const float*)d_in[1];
    const float* t_in_b   = (const float*)d_in[2];
    const float* t_out_w  = (const float*)d_in[3];
    const float* t_out_b  = (const float*)d_in[4];
    const float* t_ln1_w  = (const float*)d_in[5];
    const float* t_ln1_b  = (const float*)d_in[6];
    const float* t_lin1_w = (const float*)d_in[7];
    const float* t_lin1_b = (const float*)d_in[8];
    const float* t_lin2_w = (const float*)d_in[9];
    const float* t_lin2_b = (const float*)d_in[10];
    const float* t_ln2_w  = (const float*)d_in[11];
    const float* t_ln2_b  = (const float*)d_in[12];
    const float* r_in_w   = (const float*)d_in[13];
    const float* r_in_b   = (const float*)d_in[14];
    const float* r_out_w  = (const float*)d_in[15];
    const float* r_out_b  = (const float*)d_in[16];
    const float* r_ln1_w  = (const float*)d_in[17];
    const float* r_ln1_b  = (const float*)d_in[18];
    const float* r_lin1_w = (const float*)d_in[19];
    const float* r_lin1_b = (const float*)d_in[20];
    const float* r_lin2_w = (const float*)d_in[21];
    const float* r_lin2_b = (const float*)d_in[22];
    const float* r_ln2_w  = (const float*)d_in[23];
    const float* r_ln2_b  = (const float*)d_in[24];
    const float* lc_w     = (const float*)d_in[25];
    const float* lc_b     = (const float*)d_in[26];
    const float* up1_w    = (const float*)d_in[27];
    const float* up1_b    = (const float*)d_in[28];
    const float* up2_w    = (const float*)d_in[29];
    const float* up2_b    = (const float*)d_in[30];
    const float* n1_w     = (const float*)d_in[31];
    const float* n1_b     = (const float*)d_in[32];
    const float* n2_w     = (const float*)d_in[33];
    const float* n2_b     = (const float*)d_in[34];
    const float* l1_re    = (const float*)d_in[35];
    const float* l1_im    = (const float*)d_in[36];
    const float* lb1_re   = (const float*)d_in[39];
    const float* lb1_im   = (const float*)d_in[40];

    float* outp = (float*)d_out;

    // ---- workspace arenas (float offsets; total 21,774,336 floats = 87.1 MB) ----
    float* WS   = (float*)d_ws;
    float* Wa   = WS + 0;          // 262144
    float* Wm   = WS + 262144;     // 262144
    float* LB   = WS + 524288;     // 16384 (1024 used; [512:1024)=zero bias)
    float* BIGf = WS + 540672;     // 6291456 f32: r-qkv out; aliased ushort: t-qkv out (6291456), f1 (4194304)
    float* Bb   = WS + 6832128;    // 2097152: out-proj/lin2 f32 outs; tabC/tabS alias at start (prep only)
    float* Cc   = WS + 8929280;    // 2097152: x1/x1r f32; first half aliased as attn-bf16/u1b (dead windows)
    float* Ee   = WS + 11026432;   // 2097152: x2 -> df
    float* LLp  = WS + 13123584;   // 2097152: low -> x2r -> rf; mid-section aliased as FAlo+r_in_lo
    float* FAp  = WS + 15220736;   // 2097152: fa f32
    float* SB   = WS + 17317888;   // 1048576: ushort arena (xb -> Ccb_t -> FAhi -> Ccb_r)
    float* WBa  = WS + 18366464;   // 3407872: ushort weights (6815744)

    float* tabC = Bb;
    float* tabS = Bb + 131072;
    unsigned short* BIGu   = (unsigned short*)BIGf;
    unsigned short* AabU   = (unsigned short*)Cc;           // attn-bf16 out / u1b (Cc dead windows)
    unsigned short* SBu    = (unsigned short*)SB;
    unsigned short* FAloU  = (unsigned short*)LLp;          // 2097152 ushorts
    unsigned short* RinLoU = (unsigned short*)(LLp + 1048576); // 786432 ushorts
    unsigned short* WB     = (unsigned short*)WBa;
    const float* ZB = LB + 512;                              // zero bias

    // weight arena offsets (ushorts)
    unsigned short* w_tin  = WB + 0;        // 1536x512
    unsigned short* w_tout = WB + 786432;   // 512x512
    unsigned short* w_tl1  = WB + 1048576;  // 2048x512
    unsigned short* w_tl2  = WB + 2097152;  // 512x2048
    unsigned short* w_rin  = WB + 3145728;  // 1536x512
    unsigned short* w_rout = WB + 3932160;  // 512x512
    unsigned short* w_rl1  = WB + 4194304;  // 2048x512
    unsigned short* w_rl2  = WB + 5242880;  // 512x2048
    unsigned short* w_up1  = WB + 6291456;  // 512x512
    unsigned short* w_up2  = WB + 6553600;  // 512x512

    dim3 blk(256);

    // ---- prep ----
    tab_kernel<<<dim3(512), blk, 0, stream>>>(tabC, tabS);
    wa_kernel<<<dim3(512, 2), blk, 0, stream>>>(l1_re, l1_im, tabC, tabS, Wa);
    wm_kernel<<<dim3(512, 2), blk, 0, stream>>>(lc_w, tabC, tabS, Wm);
    lbpack_kernel<<<dim3(4), blk, 0, stream>>>(lb1_re, lb1_im, LB);
    wcvt_kernel<<<dim3(26624), blk, 0, stream>>>(t_in_w, t_out_w, t_lin1_w, t_lin2_w,
                                                 r_in_w, r_out_w, r_lin1_w, r_lin2_w,
                                                 up1_w, up2_w, WB);
    cvt_b_kernel<<<dim3(2048), blk, 0, stream>>>(x, SBu, NOUT);                       // xb

    // ---- output 1: down_x = x ----
    hipMemcpyAsync(outp + NOUT, x, (size_t)NOUT * sizeof(float), hipMemcpyDeviceToDevice, stream);

    // ---- t-TEL on x ----
    gemm_mfma<0,0,1,0><<<dim3(12, 32), blk, 0, stream>>>(SBu, w_tin, t_in_b, nullptr, BIGu, 1536, 512);
    attn_kernel<unsigned short><<<dim3(1024), blk, 0, stream>>>(BIGu, AabU);
    gemm_mfma<0,1,0,0><<<dim3(4, 32), blk, 0, stream>>>(AabU, w_tout, t_out_b, Bb, nullptr, 512, 512);
    add_ln_kernel<1><<<dim3(4096), blk, 0, stream>>>(x, Bb, t_ln1_w, t_ln1_b, Cc, SBu);     // x1 (+bf16)
    gemm_mfma<1,0,1,0><<<dim3(16, 32), blk, 0, stream>>>(SBu, w_tl1, t_lin1_b, nullptr, BIGu, 2048, 512);
    gemm_mfma<0,1,0,0><<<dim3(4, 32), blk, 0, stream>>>(BIGu, w_tl2, t_lin2_b, Bb, nullptr, 512, 2048);
    add_ln_kernel<0><<<dim3(4096), blk, 0, stream>>>(Cc, Bb, t_ln2_w, t_ln2_b, Ee, nullptr); // x2
    relu_bln_kernel<<<dim3(128), blk, 0, stream>>>(Ee, n1_w, n1_b, Ee);                      // df

    // ---- freq branch (f32) ----
    gemm_k<1><<<dim3(8, 64), blk, 0, stream>>>(x, Wa, LB, LLp, NROW, 512, 512);              // crelu(low)
    cattn_kernel<<<dim3(128), blk, 0, stream>>>(LLp);                                        // low += cattn
    gemm_k<0><<<dim3(8, 64), blk, 0, stream>>>(LLp, Wm, lc_b, FAp, NROW, 512, 512);          // fa
    hipMemcpyAsync(outp + 2 * NOUT, FAp, (size_t)NOUT * sizeof(float), hipMemcpyDeviceToDevice, stream);

    // fa -> hi/lo bf16; r_in_w lo
    cvt_hilo_kernel<<<dim3(2048), blk, 0, stream>>>(FAp, SBu, FAloU, NOUT);
    cvt_lo_kernel<<<dim3(768), blk, 0, stream>>>(r_in_w, w_rin, RinLoU, 786432);

    // ---- upsample ----
    gemm_mfma<0,0,1,0><<<dim3(4, 32), blk, 0, stream>>>(SBu, w_up1, up1_b, nullptr, AabU, 512, 512);       // u1
    gemm_mfma<0,1,0,0><<<dim3(4, 32), blk, 0, stream>>>(AabU, w_up2, up2_b, outp + 3 * NOUT, nullptr, 512, 512);

    // ---- r-TEL on fa (qkv in 3-pass hi/lo for score fidelity) ----
    gemm_mfma<0,1,0,0><<<dim3(12, 32), blk, 0, stream>>>(SBu,   w_rin, r_in_b, BIGf, nullptr, 1536, 512);
    gemm_mfma<0,1,0,1><<<dim3(12, 32), blk, 0, stream>>>(FAloU, w_rin, ZB,     BIGf, nullptr, 1536, 512);
    gemm_mfma<0,1,0,1><<<dim3(12, 32), blk, 0, stream>>>(SBu,   RinLoU, ZB,    BIGf, nullptr, 1536, 512);
    attn_kernel<float><<<dim3(1024), blk, 0, stream>>>(BIGf, AabU);
    gemm_mfma<0,1,0,0><<<dim3(4, 32), blk, 0, stream>>>(AabU, w_rout, r_out_b, Bb, nullptr, 512, 512);
    add_ln_kernel<1><<<dim3(4096), blk, 0, stream>>>(FAp, Bb, r_ln1_w, r_ln1_b, Cc, SBu);    // x1r (+bf16)
    gemm_mfma<1,0,1,0><<<dim3(16, 32), blk, 0, stream>>>(SBu, w_rl1, r_lin1_b, nullptr, BIGu, 2048, 512);
    gemm_mfma<0,1,0,0><<<dim3(4, 32), blk, 0, stream>>>(BIGu, w_rl2, r_lin2_b, Bb, nullptr, 512, 2048);
    add_ln_kernel<0><<<dim3(4096), blk, 0, stream>>>(Cc, Bb, r_ln2_w, r_ln2_b, LLp, nullptr); // x2r
    relu_bln_kernel<<<dim3(128), blk, 0, stream>>>(LLp, n2_w, n2_b, LLp);                     // rf

    // ---- output 0: res = df + rf ----
    add_f32_kernel<<<dim3(2048), blk, 0, stream>>>(Ee, LLp, outp, NOUT);
}

// Round 5
// 681.291 us; speedup vs baseline: 2.6513x; 1.2810x over previous
//
#include <hip/hip_runtime.h>
#include <math.h>

// NoiScaleModule: B=128, C=32(seq), S=512(d_model), EMB=256, NHEAD=8, DFF=2048
// All tensors FLOAT32. Outputs concat flat: res[2M], down_x[2M], fa[2M], up[2M]
//
// Simplifications:
//  - 'high' freq branch dead (xcat == low); h1/hb1 unused.
//  - rfft folded into low-projection (Wa); irfft+linear_change folded (Wm).
//  - big GEMMs on bf16 MFMA (16x16x32, 128x128 tile, global_load_lds);
//    freq GEMMs + r-qkv use fused hi/lo bf16 3-product MFMA (f32-grade, one dispatch).
//  - cattn: 2 blocks/batch, LDS-resident X (XOR swizzle), emits hi/lo bf16 directly.
// R4 bug fixed: BbF moved to BIGf+4194304 so lin2's C-write cannot overlap f1 (A) reads.

#define NROW 4096
#define NOUT 2097152

typedef __attribute__((ext_vector_type(8))) short short8;
typedef __attribute__((ext_vector_type(4))) float floatx4;

__device__ __forceinline__ unsigned short f2bf(float f) {
    union { float f; unsigned u; } v; v.f = f;
    return (unsigned short)((v.u + 0x7fffu + ((v.u >> 16) & 1u)) >> 16);
}
__device__ __forceinline__ float bf2f(unsigned short h) {
    union { unsigned u; float f; } v; v.u = ((unsigned)h) << 16;
    return v.f;
}
__device__ __forceinline__ float ldv(const float* p, size_t i) { return p[i]; }
__device__ __forceinline__ float ldv(const unsigned short* p, size_t i) { return bf2f(p[i]); }

__device__ __forceinline__ void gload16(const unsigned short* g, unsigned short* l) {
    __builtin_amdgcn_global_load_lds((const __attribute__((address_space(1))) void*)g,
                                     (__attribute__((address_space(3))) void*)l, 16, 0, 0);
}

// ---------------- prep: cos/sin tables tab[n][k], n<512, k<256 ----------------
__global__ __launch_bounds__(256) void tab_kernel(float* __restrict__ tabC, float* __restrict__ tabS)
{
    int n = blockIdx.x, k = threadIdx.x;
    int m = (n * k) & 511;
    float th = (float)m * 0.01227184630308513f;  // 2*pi/512
    float s, c; sincosf(th, &s, &c);
    tabC[n * 256 + k] = c;
    tabS[n * 256 + k] = s;
}

__global__ __launch_bounds__(256) void wa_kernel(const float* __restrict__ l1_re, const float* __restrict__ l1_im,
                                                 const float* __restrict__ tabC, const float* __restrict__ tabS,
                                                 float* __restrict__ Wa)
{
    int n  = blockIdx.x;
    int ep = blockIdx.y * 256 + threadIdx.x;
    const float inv = 0.04419417382415922f;  // 1/sqrt(512)
    float acc = 0.f;
    if (ep < 256) {
        for (int k = 0; k < 128; ++k) {
            float c = tabC[n * 256 + k], s = tabS[n * 256 + k];
            acc += c * l1_re[k * 256 + ep] + s * l1_im[k * 256 + ep];
        }
    } else {
        int e = ep - 256;
        for (int k = 0; k < 128; ++k) {
            float c = tabC[n * 256 + k], s = tabS[n * 256 + k];
            acc += c * l1_im[k * 256 + e] - s * l1_re[k * 256 + e];
        }
    }
    Wa[(size_t)ep * 512 + n] = acc * inv;
}

__global__ __launch_bounds__(256) void wm_kernel(const float* __restrict__ lc_w,
                                                 const float* __restrict__ tabC, const float* __restrict__ tabS,
                                                 float* __restrict__ Wm)
{
    int s  = blockIdx.x;
    int kk = blockIdx.y * 256 + threadIdx.x;
    const float inv = 0.04419417382415922f;
    float acc = 0.f;
    if (kk < 256) {
        int k = kk;
        for (int n = 0; n < 512; ++n) acc += tabC[n * 256 + k] * lc_w[s * 512 + n];
        acc *= (k == 0) ? inv : 2.f * inv;
    } else {
        int k = kk - 256;
        if (k == 0) acc = 0.f;
        else {
            for (int n = 0; n < 512; ++n) acc += tabS[n * 256 + k] * lc_w[s * 512 + n];
            acc *= -2.f * inv;
        }
    }
    Wm[(size_t)s * 512 + kk] = acc;
}

// LB[0:512] = [lb1_re|lb1_im]; LB[512:1024] = 0
__global__ __launch_bounds__(256) void lbpack_kernel(const float* __restrict__ re, const float* __restrict__ im,
                                                     float* __restrict__ out)
{
    int i = threadIdx.x + blockIdx.x * 256;  // 0..1023
    out[i] = (i < 256) ? re[i] : (i < 512 ? im[i - 256] : 0.f);
}

// convert all 10 weight matrices to bf16 into one arena
__global__ __launch_bounds__(256) void wcvt_kernel(
    const float* s0, const float* s1, const float* s2, const float* s3, const float* s4,
    const float* s5, const float* s6, const float* s7, const float* s8, const float* s9,
    unsigned short* __restrict__ o)
{
    int i = blockIdx.x * 256 + threadIdx.x;
    if (i >= 6815744) return;
    const float* s; int off;
    if (i < 3145728) {
        if (i < 1048576) { if (i < 786432) { s = s0; off = 0; } else { s = s1; off = 786432; } }
        else             { if (i < 2097152) { s = s2; off = 1048576; } else { s = s3; off = 2097152; } }
    } else {
        if (i < 5242880) {
            if (i < 3932160) { s = s4; off = 3145728; }
            else if (i < 4194304) { s = s5; off = 3932160; }
            else { s = s6; off = 4194304; }
        } else {
            if (i < 6291456) { s = s7; off = 5242880; }
            else if (i < 6553600) { s = s8; off = 6291456; }
            else { s = s9; off = 6553600; }
        }
    }
    o[i] = f2bf(s[i - off]);
}

__global__ __launch_bounds__(256) void cvt_hilo_kernel(const float* __restrict__ a, unsigned short* __restrict__ hi,
                                                       unsigned short* __restrict__ lo, int n)
{
    for (int i = blockIdx.x * 256 + threadIdx.x; i < n; i += gridDim.x * 256) {
        unsigned short h = f2bf(a[i]);
        hi[i] = h;
        lo[i] = f2bf(a[i] - bf2f(h));
    }
}
__global__ __launch_bounds__(256) void cvt_lo_kernel(const float* __restrict__ a, const unsigned short* __restrict__ hi,
                                                     unsigned short* __restrict__ lo, int n)
{
    for (int i = blockIdx.x * 256 + threadIdx.x; i < n; i += gridDim.x * 256)
        lo[i] = f2bf(a[i] - bf2f(hi[i]));
}

// ---------------- MFMA GEMM: C[M,N] = A[M,K](bf16) @ W[N,K](bf16)^T + bias ----------------
// 128x128 tile, BK=32, 4 waves (2x2), each wave 64x64 via 4x4 mfma_16x16x32_bf16.
template <int ACT, int WF, int WBF, int ACCUM>
__global__ __launch_bounds__(256) void gemm_mfma(
    const unsigned short* __restrict__ A, const unsigned short* __restrict__ W,
    const float* __restrict__ bias, float* __restrict__ Cf, unsigned short* __restrict__ Cb,
    int N, int K)
{
    __shared__ unsigned short As[128 * 32];
    __shared__ unsigned short Bs[128 * 32];
    const int tid = threadIdx.x;
    const int wave = tid >> 6, lane = tid & 63;
    const int m0 = blockIdx.y * 128, n0 = blockIdx.x * 128;
    const int sr = lane >> 2, sc = (lane & 3) * 8;
    const unsigned short* aS0 = A + (size_t)(m0 + wave * 32 + sr) * K + sc;
    const unsigned short* aS1 = aS0 + (size_t)16 * K;
    const unsigned short* wS0 = W + (size_t)(n0 + wave * 32 + sr) * K + sc;
    const unsigned short* wS1 = wS0 + (size_t)16 * K;
    unsigned short* aD0 = &As[(wave * 32) * 32];
    unsigned short* aD1 = &As[(wave * 32 + 16) * 32];
    unsigned short* bD0 = &Bs[(wave * 32) * 32];
    unsigned short* bD1 = &Bs[(wave * 32 + 16) * 32];
    const int wm = (wave >> 1) * 64, wn = (wave & 1) * 64;
    const int fr = lane & 15, fko = (lane >> 4) * 8;

    floatx4 acc[4][4];
#pragma unroll
    for (int i = 0; i < 4; ++i)
#pragma unroll
        for (int j = 0; j < 4; ++j) acc[i][j] = (floatx4){0.f, 0.f, 0.f, 0.f};

    for (int k0 = 0; k0 < K; k0 += 32) {
        gload16(aS0 + k0, aD0);
        gload16(aS1 + k0, aD1);
        gload16(wS0 + k0, bD0);
        gload16(wS1 + k0, bD1);
        __syncthreads();
        short8 af[4], bfr[4];
#pragma unroll
        for (int i = 0; i < 4; ++i) af[i] = *(const short8*)&As[(wm + i * 16 + fr) * 32 + fko];
#pragma unroll
        for (int j = 0; j < 4; ++j) bfr[j] = *(const short8*)&Bs[(wn + j * 16 + fr) * 32 + fko];
#pragma unroll
        for (int i = 0; i < 4; ++i)
#pragma unroll
            for (int j = 0; j < 4; ++j)
                acc[i][j] = __builtin_amdgcn_mfma_f32_16x16x32_bf16(af[i], bfr[j], acc[i][j], 0, 0, 0);
        __syncthreads();
    }
    const int r0 = m0 + wm + (lane >> 4) * 4;
#pragma unroll
    for (int i = 0; i < 4; ++i) {
#pragma unroll
        for (int j = 0; j < 4; ++j) {
            int n = n0 + wn + j * 16 + fr;
            float bv = bias[n];
#pragma unroll
            for (int r = 0; r < 4; ++r) {
                int m = r0 + i * 16 + r;
                size_t idx = (size_t)m * N + n;
                float v = acc[i][j][r] + bv;
                if (ACT) v = fmaxf(v, 0.f);
                if (ACCUM) v += Cf[idx];
                if (WF) Cf[idx] = v;
                if (WBF) Cb[idx] = f2bf(v);
            }
        }
    }
}

// ---------------- fused hi/lo 3-product MFMA GEMM: C = (Ah+Al)@(Wh+Wl)^T + bias (f32 out) ----
// acc += Ah*Wh + Al*Wh + Ah*Wl  (drops lo*lo; rel err ~1.6e-5)
template <int ACT>
__global__ __launch_bounds__(256) void gemm_mfma3(
    const unsigned short* __restrict__ Ah, const unsigned short* __restrict__ Al,
    const unsigned short* __restrict__ Wh, const unsigned short* __restrict__ Wl,
    const float* __restrict__ bias, float* __restrict__ Cf, int N, int K)
{
    __shared__ unsigned short Ash[128 * 32];
    __shared__ unsigned short Asl[128 * 32];
    __shared__ unsigned short Bsh[128 * 32];
    __shared__ unsigned short Bsl[128 * 32];
    const int tid = threadIdx.x;
    const int wave = tid >> 6, lane = tid & 63;
    const int m0 = blockIdx.y * 128, n0 = blockIdx.x * 128;
    const int sr = lane >> 2, sc = (lane & 3) * 8;
    const size_t aoff0 = (size_t)(m0 + wave * 32 + sr) * K + sc;
    const size_t aoff1 = aoff0 + (size_t)16 * K;
    const size_t woff0 = (size_t)(n0 + wave * 32 + sr) * K + sc;
    const size_t woff1 = woff0 + (size_t)16 * K;
    const int l0 = (wave * 32) * 32, l1 = (wave * 32 + 16) * 32;
    const int wm = (wave >> 1) * 64, wn = (wave & 1) * 64;
    const int fr = lane & 15, fko = (lane >> 4) * 8;

    floatx4 acc[4][4];
#pragma unroll
    for (int i = 0; i < 4; ++i)
#pragma unroll
        for (int j = 0; j < 4; ++j) acc[i][j] = (floatx4){0.f, 0.f, 0.f, 0.f};

    for (int k0 = 0; k0 < K; k0 += 32) {
        gload16(Ah + aoff0 + k0, &Ash[l0]);
        gload16(Ah + aoff1 + k0, &Ash[l1]);
        gload16(Al + aoff0 + k0, &Asl[l0]);
        gload16(Al + aoff1 + k0, &Asl[l1]);
        gload16(Wh + woff0 + k0, &Bsh[l0]);
        gload16(Wh + woff1 + k0, &Bsh[l1]);
        gload16(Wl + woff0 + k0, &Bsl[l0]);
        gload16(Wl + woff1 + k0, &Bsl[l1]);
        __syncthreads();
        short8 ah[4], al[4], bh[4], bl[4];
#pragma unroll
        for (int i = 0; i < 4; ++i) {
            ah[i] = *(const short8*)&Ash[(wm + i * 16 + fr) * 32 + fko];
            al[i] = *(const short8*)&Asl[(wm + i * 16 + fr) * 32 + fko];
        }
#pragma unroll
        for (int j = 0; j < 4; ++j) {
            bh[j] = *(const short8*)&Bsh[(wn + j * 16 + fr) * 32 + fko];
            bl[j] = *(const short8*)&Bsl[(wn + j * 16 + fr) * 32 + fko];
        }
#pragma unroll
        for (int i = 0; i < 4; ++i)
#pragma unroll
            for (int j = 0; j < 4; ++j) {
                acc[i][j] = __builtin_amdgcn_mfma_f32_16x16x32_bf16(al[i], bh[j], acc[i][j], 0, 0, 0);
                acc[i][j] = __builtin_amdgcn_mfma_f32_16x16x32_bf16(ah[i], bl[j], acc[i][j], 0, 0, 0);
                acc[i][j] = __builtin_amdgcn_mfma_f32_16x16x32_bf16(ah[i], bh[j], acc[i][j], 0, 0, 0);
            }
        __syncthreads();
    }
    const int r0 = m0 + wm + (lane >> 4) * 4;
#pragma unroll
    for (int i = 0; i < 4; ++i) {
#pragma unroll
        for (int j = 0; j < 4; ++j) {
            int n = n0 + wn + j * 16 + fr;
            float bv = bias[n];
#pragma unroll
            for (int r = 0; r < 4; ++r) {
                int m = r0 + i * 16 + r;
                float v = acc[i][j][r] + bv;
                if (ACT) v = fmaxf(v, 0.f);
                Cf[(size_t)m * N + n] = v;
            }
        }
    }
}

// ---------------- TEL attention: one block per (batch, head); bf16 out ----------------
template <typename T>
__global__ __launch_bounds__(256) void attn_kernel(const T* __restrict__ qkv, unsigned short* __restrict__ outb)
{
    const int b = blockIdx.x >> 3;
    const int h = blockIdx.x & 7;
    __shared__ float qs[32][65], ks[32][65], vs[32][65];
    __shared__ float ps[32][33];
    const int tid = threadIdx.x;
    for (int i = tid; i < 2048; i += 256) {
        int s = i >> 6, d = i & 63;
        size_t base = ((size_t)(b * 32 + s)) * 1536 + h * 64 + d;
        qs[s][d] = ldv(qkv, base);
        ks[s][d] = ldv(qkv, base + 512);
        vs[s][d] = ldv(qkv, base + 1024);
    }
    __syncthreads();
    for (int i = tid; i < 1024; i += 256) {
        int si = i >> 5, sj = i & 31;
        float acc = 0.f;
#pragma unroll 8
        for (int d = 0; d < 64; ++d) acc += qs[si][d] * ks[sj][d];
        ps[si][sj] = acc * 0.125f;
    }
    __syncthreads();
    if (tid < 32) {
        float mx = -1e30f;
        for (int j = 0; j < 32; ++j) mx = fmaxf(mx, ps[tid][j]);
        float sum = 0.f;
        for (int j = 0; j < 32; ++j) { float e = __expf(ps[tid][j] - mx); ps[tid][j] = e; sum += e; }
        float inv = 1.f / sum;
        for (int j = 0; j < 32; ++j) ps[tid][j] *= inv;
    }
    __syncthreads();
    for (int i = tid; i < 2048; i += 256) {
        int s = i >> 6, d = i & 63;
        float acc = 0.f;
#pragma unroll 8
        for (int k = 0; k < 32; ++k) acc += ps[s][k] * vs[k][d];
        outb[((size_t)(b * 32 + s)) * 512 + h * 64 + d] = f2bf(acc);
    }
}

// ---------------- complex self-attention v2: LDS-resident, grid (128 batch, 2 half) ----------
// Reads LL f32 (low), writes LLout = low + cattn(low) as hi/lo bf16 pair.
__global__ __launch_bounds__(256) void cattn2_kernel(const float* __restrict__ LL,
                                                     unsigned short* __restrict__ outHi,
                                                     unsigned short* __restrict__ outLo)
{
    extern __shared__ float Xs[];
    __shared__ float Pr[16][33], Pi[16][33];
    const int b = blockIdx.x, half = blockIdx.y;
    const int tid = threadIdx.x;
    const float* base = LL + (size_t)b * 16384;
    for (int i = tid; i < 16384; i += 256) {
        int c = i >> 9, e = i & 511;
        Xs[e * 32 + ((c ^ e) & 31)] = base[i];
    }
    __syncthreads();
    {
        const int li0 = tid >> 5, li1 = li0 + 8;
        const int ci0 = half * 16 + li0, ci1 = half * 16 + li1;
        const int ck = tid & 31;
        float ar0 = 0.f, ai0 = 0.f, ar1 = 0.f, ai1 = 0.f;
        for (int er = 0; er < 256; ++er) {
            const int sw = er & 31;
            float yr = Xs[er * 32 + ((ck ^ sw) & 31)];
            float yi = Xs[(er + 256) * 32 + ((ck ^ sw) & 31)];
            float xr0 = Xs[er * 32 + ((ci0 ^ sw) & 31)];
            float xi0 = Xs[(er + 256) * 32 + ((ci0 ^ sw) & 31)];
            float xr1 = Xs[er * 32 + ((ci1 ^ sw) & 31)];
            float xi1 = Xs[(er + 256) * 32 + ((ci1 ^ sw) & 31)];
            ar0 += xr0 * yr - xi0 * yi;  ai0 += xr0 * yi + xi0 * yr;
            ar1 += xr1 * yr - xi1 * yi;  ai1 += xr1 * yi + xi1 * yr;
        }
        Pr[li0][ck] = ar0 * 0.0625f;  Pi[li0][ck] = ai0 * 0.0625f;
        Pr[li1][ck] = ar1 * 0.0625f;  Pi[li1][ck] = ai1 * 0.0625f;
    }
    __syncthreads();
    if (tid < 32) {
        int r = tid & 15;
        float (*P)[33] = (tid < 16) ? Pr : Pi;
        float mx = -1e30f;
        for (int j = 0; j < 32; ++j) mx = fmaxf(mx, P[r][j]);
        float s = 0.f;
        for (int j = 0; j < 32; ++j) { float e = __expf(P[r][j] - mx); P[r][j] = e; s += e; }
        float inv = 1.f / s;
        for (int j = 0; j < 32; ++j) P[r][j] *= inv;
    }
    __syncthreads();
    const int er = tid;
    const int sw = er & 31;
    float accr[16], acci[16];
#pragma unroll
    for (int t = 0; t < 16; ++t) { accr[t] = 0.f; acci[t] = 0.f; }
    for (int k = 0; k < 32; ++k) {
        float yr = Xs[er * 32 + ((k ^ sw) & 31)];
        float yi = Xs[(er + 256) * 32 + ((k ^ sw) & 31)];
#pragma unroll
        for (int t = 0; t < 16; ++t) {
            float pr = Pr[t][k], pi = Pi[t][k];
            accr[t] += pr * yr - pi * yi;
            acci[t] += pr * yi + pi * yr;
        }
    }
#pragma unroll
    for (int t = 0; t < 16; ++t) {
        int c = half * 16 + t;
        float vr = Xs[er * 32 + ((c ^ sw) & 31)] + accr[t];
        float vi = Xs[(er + 256) * 32 + ((c ^ sw) & 31)] + acci[t];
        size_t ir = (size_t)b * 16384 + (size_t)c * 512 + er;
        unsigned short hr = f2bf(vr), hi2 = f2bf(vi);
        outHi[ir] = hr;        outLo[ir] = f2bf(vr - bf2f(hr));
        outHi[ir + 256] = hi2; outLo[ir + 256] = f2bf(vi - bf2f(hi2));
    }
}

// ---------------- residual add + LayerNorm over last dim (512), optional bf16 copy ----------
template <int WBF>
__global__ __launch_bounds__(256) void add_ln_kernel(const float* __restrict__ resid, const float* __restrict__ y,
                                                     const float* __restrict__ w, const float* __restrict__ b,
                                                     float* __restrict__ outf, unsigned short* __restrict__ outb)
{
    const int row = blockIdx.x;
    const int tid = threadIdx.x;
    const size_t base = (size_t)row * 512;
    float v0 = resid[base + tid] + y[base + tid];
    float v1 = resid[base + 256 + tid] + y[base + 256 + tid];
    float s = v0 + v1, q = v0 * v0 + v1 * v1;
    for (int off = 32; off; off >>= 1) { s += __shfl_down(s, off); q += __shfl_down(q, off); }
    __shared__ float sw[4], qw[4], ms, is;
    int wid = tid >> 6, lane = tid & 63;
    if (lane == 0) { sw[wid] = s; qw[wid] = q; }
    __syncthreads();
    if (tid == 0) {
        float S = sw[0] + sw[1] + sw[2] + sw[3];
        float Q = qw[0] + qw[1] + qw[2] + qw[3];
        float m = S * (1.f / 512.f);
        ms = m;
        is = rsqrtf(Q * (1.f / 512.f) - m * m + 1e-5f);
    }
    __syncthreads();
    float m = ms, inv = is;
    float o0 = (v0 - m) * inv * w[tid] + b[tid];
    float o1 = (v1 - m) * inv * w[256 + tid] + b[256 + tid];
    outf[base + tid] = o0;
    outf[base + 256 + tid] = o1;
    if (WBF) { outb[base + tid] = f2bf(o0); outb[base + 256 + tid] = f2bf(o1); }
}

// ---------------- relu + LayerNorm over (C,S)=16384 per batch ----------------
__global__ __launch_bounds__(256) void relu_bln_kernel(const float* __restrict__ xin,
                                                       const float* __restrict__ w, const float* __restrict__ b,
                                                       float* __restrict__ out)
{
    const int bb = blockIdx.x;
    const int tid = threadIdx.x;
    const float* xp = xin + (size_t)bb * 16384;
    float s = 0.f, q = 0.f;
    for (int i = tid; i < 16384; i += 256) { float v = fmaxf(xp[i], 0.f); s += v; q += v * v; }
    for (int off = 32; off; off >>= 1) { s += __shfl_down(s, off); q += __shfl_down(q, off); }
    __shared__ float sw[4], qw[4], ms, is;
    int wid = tid >> 6, lane = tid & 63;
    if (lane == 0) { sw[wid] = s; qw[wid] = q; }
    __syncthreads();
    if (tid == 0) {
        float S = sw[0] + sw[1] + sw[2] + sw[3];
        float Q = qw[0] + qw[1] + qw[2] + qw[3];
        float m = S * (1.f / 16384.f);
        ms = m;
        is = rsqrtf(Q * (1.f / 16384.f) - m * m + 1e-5f);
    }
    __syncthreads();
    float m = ms, inv = is;
    float* op = out + (size_t)bb * 16384;
    for (int i = tid; i < 16384; i += 256) {
        float v = fmaxf(xp[i], 0.f);
        op[i] = (v - m) * inv * w[i] + b[i];
    }
}

__global__ __launch_bounds__(256) void add_f32_kernel(const float* __restrict__ a, const float* __restrict__ bsrc,
                                                      float* __restrict__ o, int n)
{
    for (int i = blockIdx.x * 256 + threadIdx.x; i < n; i += gridDim.x * 256) o[i] = a[i] + bsrc[i];
}

extern "C" void kernel_launch(void* const* d_in, const int* in_sizes, int n_in,
                              void* d_out, int out_size, void* d_ws, size_t ws_size,
                              hipStream_t stream)
{
    (void)in_sizes; (void)n_in; (void)out_size; (void)ws_size;
    const float* x        = (const float*)d_in[0];
    const float* t_in_w   = (const float*)d_in[1];
    const float* t_in_b   = (const float*)d_in[2];
    const float* t_out_w  = (const float*)d_in[3];
    const float* t_out_b  = (const float*)d_in[4];
    const float* t_ln1_w  = (const float*)d_in[5];
    const float* t_ln1_b  = (const float*)d_in[6];
    const float* t_lin1_w = (const float*)d_in[7];
    const float* t_lin1_b = (const float*)d_in[8];
    const float* t_lin2_w = (const float*)d_in[9];
    const float* t_lin2_b = (const float*)d_in[10];
    const float* t_ln2_w  = (const float*)d_in[11];
    const float* t_ln2_b  = (const float*)d_in[12];
    const float* r_in_w   = (const float*)d_in[13];
    const float* r_in_b   = (const float*)d_in[14];
    const float* r_out_w  = (const float*)d_in[15];
    const float* r_out_b  = (const float*)d_in[16];
    const float* r_ln1_w  = (const float*)d_in[17];
    const float* r_ln1_b  = (const float*)d_in[18];
    const float* r_lin1_w = (const float*)d_in[19];
    const float* r_lin1_b = (const float*)d_in[20];
    const float* r_lin2_w = (const float*)d_in[21];
    const float* r_lin2_b = (const float*)d_in[22];
    const float* r_ln2_w  = (const float*)d_in[23];
    const float* r_ln2_b  = (const float*)d_in[24];
    const float* lc_w     = (const float*)d_in[25];
    const float* lc_b     = (const float*)d_in[26];
    const float* up1_w    = (const float*)d_in[27];
    const float* up1_b    = (const float*)d_in[28];
    const float* up2_w    = (const float*)d_in[29];
    const float* up2_b    = (const float*)d_in[30];
    const float* n1_w     = (const float*)d_in[31];
    const float* n1_b     = (const float*)d_in[32];
    const float* n2_w     = (const float*)d_in[33];
    const float* n2_b     = (const float*)d_in[34];
    const float* l1_re    = (const float*)d_in[35];
    const float* l1_im    = (const float*)d_in[36];
    const float* lb1_re   = (const float*)d_in[39];
    const float* lb1_im   = (const float*)d_in[40];

    float* outp = (float*)d_out;

    // ---- workspace (float offsets; total 21,774,336 f = 87.1 MB, same as validated) ----
    float* WS   = (float*)d_ws;
    float* WaF  = WS + 0;          // 262144 f32 Wa; later WmH/WmL ushort
    float* WmF  = WS + 262144;     // 262144 f32 Wm
    float* LB   = WS + 524288;     // 16384 ([0:512) lb bias, [512:1024) zero)
    float* BIGf = WS + 540672;     // 6291456: r-qkv f32 (full) | f1 bf16 [0:4194304) | BbF [4194304:6291456)
    float* Cc   = WS + 6832128;    // 2097152: x1/x1r f32; AabU ushort alias lower half
    float* Ee   = WS + 8929280;    // 2097152: x2->df; tabC/tabS alias (prep only)
    float* LLp  = WS + 11026432;   // 2097152: low f32; rin_lo ushort alias after cattn
    float* FAp  = WS + 13123584;   // 2097152: fa f32; WaH/WaL ushort alias (prep only)
    float* U1f  = WS + 15220736;   // 1048576: ushort x_hi -> x1b -> x1rb
    float* U2f  = WS + 16269312;   // 1048576: ushort x_lo -> LL_hi -> fa_hi
    float* U3f  = WS + 17317888;   // 1048576: ushort LL_lo -> fa_lo
    float* WBf  = WS + 18366464;   // 3407872: ushort weights (6815744)

    float* BbF  = BIGf + 4194304;  // R4 fix: disjoint from f1 bf16 alias [0:4194304)
    float* tabC = Ee;
    float* tabS = Ee + 131072;
    unsigned short* BIGu   = (unsigned short*)BIGf;
    unsigned short* AabU   = (unsigned short*)Cc;
    unsigned short* rinLoU = (unsigned short*)LLp;            // 786432 u
    unsigned short* WaHu   = (unsigned short*)FAp;            // 262144 u
    unsigned short* WaLu   = (unsigned short*)(FAp + 131072); // 262144 u
    unsigned short* WmHu   = (unsigned short*)WaF;            // 262144 u
    unsigned short* WmLu   = (unsigned short*)(WaF + 131072); // 262144 u
    unsigned short* U1u    = (unsigned short*)U1f;
    unsigned short* U2u    = (unsigned short*)U2f;
    unsigned short* U3u    = (unsigned short*)U3f;
    unsigned short* WB     = (unsigned short*)WBf;

    unsigned short* w_tin  = WB + 0;        // 1536x512
    unsigned short* w_tout = WB + 786432;   // 512x512
    unsigned short* w_tl1  = WB + 1048576;  // 2048x512
    unsigned short* w_tl2  = WB + 2097152;  // 512x2048
    unsigned short* w_rin  = WB + 3145728;  // 1536x512
    unsigned short* w_rout = WB + 3932160;  // 512x512
    unsigned short* w_rl1  = WB + 4194304;  // 2048x512
    unsigned short* w_rl2  = WB + 5242880;  // 512x2048
    unsigned short* w_up1  = WB + 6291456;  // 512x512
    unsigned short* w_up2  = WB + 6553600;  // 512x512

    dim3 blk(256);

    // ---- prep ----
    tab_kernel<<<dim3(512), blk, 0, stream>>>(tabC, tabS);
    wa_kernel<<<dim3(512, 2), blk, 0, stream>>>(l1_re, l1_im, tabC, tabS, WaF);
    wm_kernel<<<dim3(512, 2), blk, 0, stream>>>(lc_w, tabC, tabS, WmF);
    cvt_hilo_kernel<<<dim3(1024), blk, 0, stream>>>(WaF, WaHu, WaLu, 262144);
    cvt_hilo_kernel<<<dim3(1024), blk, 0, stream>>>(WmF, WmHu, WmLu, 262144);
    lbpack_kernel<<<dim3(4), blk, 0, stream>>>(lb1_re, lb1_im, LB);
    wcvt_kernel<<<dim3(26624), blk, 0, stream>>>(t_in_w, t_out_w, t_lin1_w, t_lin2_w,
                                                 r_in_w, r_out_w, r_lin1_w, r_lin2_w,
                                                 up1_w, up2_w, WB);
    cvt_hilo_kernel<<<dim3(2048), blk, 0, stream>>>(x, U1u, U2u, NOUT);         // x hi/lo

    // ---- output 1: down_x = x ----
    hipMemcpyAsync(outp + NOUT, x, (size_t)NOUT * sizeof(float), hipMemcpyDeviceToDevice, stream);

    // ---- freq branch ----
    gemm_mfma3<1><<<dim3(4, 32), blk, 0, stream>>>(U1u, U2u, WaHu, WaLu, LB, LLp, 512, 512);     // crelu(low)
    cattn2_kernel<<<dim3(128, 2), blk, 65536, stream>>>(LLp, U2u, U3u);                           // LL hi/lo
    gemm_mfma3<0><<<dim3(4, 32), blk, 0, stream>>>(U2u, U3u, WmHu, WmLu, lc_b, FAp, 512, 512);   // fa
    hipMemcpyAsync(outp + 2 * NOUT, FAp, (size_t)NOUT * sizeof(float), hipMemcpyDeviceToDevice, stream);
    cvt_lo_kernel<<<dim3(768), blk, 0, stream>>>(r_in_w, w_rin, rinLoU, 786432);                 // rin lo (LLp dead)

    // ---- t-TEL on x ----
    gemm_mfma<0,0,1,0><<<dim3(12, 32), blk, 0, stream>>>(U1u, w_tin, t_in_b, nullptr, BIGu, 1536, 512);
    attn_kernel<unsigned short><<<dim3(1024), blk, 0, stream>>>(BIGu, AabU);
    gemm_mfma<0,1,0,0><<<dim3(4, 32), blk, 0, stream>>>(AabU, w_tout, t_out_b, BbF, nullptr, 512, 512);
    add_ln_kernel<1><<<dim3(4096), blk, 0, stream>>>(x, BbF, t_ln1_w, t_ln1_b, Cc, U1u);         // x1 (+bf16)
    gemm_mfma<1,0,1,0><<<dim3(16, 32), blk, 0, stream>>>(U1u, w_tl1, t_lin1_b, nullptr, BIGu, 2048, 512);
    gemm_mfma<0,1,0,0><<<dim3(4, 32), blk, 0, stream>>>(BIGu, w_tl2, t_lin2_b, BbF, nullptr, 512, 2048);
    add_ln_kernel<0><<<dim3(4096), blk, 0, stream>>>(Cc, BbF, t_ln2_w, t_ln2_b, Ee, nullptr);    // x2
    relu_bln_kernel<<<dim3(128), blk, 0, stream>>>(Ee, n1_w, n1_b, Ee);                          // df

    // fa -> hi/lo bf16 (U2/U3; LL hi/lo dead after Wm-GEMM)
    cvt_hilo_kernel<<<dim3(2048), blk, 0, stream>>>(FAp, U2u, U3u, NOUT);

    // ---- upsample ----
    gemm_mfma<0,0,1,0><<<dim3(4, 32), blk, 0, stream>>>(U2u, w_up1, up1_b, nullptr, AabU, 512, 512);
    gemm_mfma<0,1,0,0><<<dim3(4, 32), blk, 0, stream>>>(AabU, w_up2, up2_b, outp + 3 * NOUT, nullptr, 512, 512);

    // ---- r-TEL on fa (fused hi/lo qkv) ----
    gemm_mfma3<0><<<dim3(12, 32), blk, 0, stream>>>(U2u, U3u, w_rin, rinLoU, r_in_b, BIGf, 1536, 512);
    attn_kernel<float><<<dim3(1024), blk, 0, stream>>>(BIGf, AabU);
    gemm_mfma<0,1,0,0><<<dim3(4, 32), blk, 0, stream>>>(AabU, w_rout, r_out_b, BbF, nullptr, 512, 512);
    add_ln_kernel<1><<<dim3(4096), blk, 0, stream>>>(FAp, BbF, r_ln1_w, r_ln1_b, Cc, U1u);       // x1r (+bf16)
    gemm_mfma<1,0,1,0><<<dim3(16, 32), blk, 0, stream>>>(U1u, w_rl1, r_lin1_b, nullptr, BIGu, 2048, 512);
    gemm_mfma<0,1,0,0><<<dim3(4, 32), blk, 0, stream>>>(BIGu, w_rl2, r_lin2_b, BbF, nullptr, 512, 2048);
    add_ln_kernel<0><<<dim3(4096), blk, 0, stream>>>(Cc, BbF, r_ln2_w, r_ln2_b, LLp, nullptr);   // x2r
    relu_bln_kernel<<<dim3(128), blk, 0, stream>>>(LLp, n2_w, n2_b, LLp);                        // rf

    // ---- output 0: res = df + rf ----
    add_f32_kernel<<<dim3(2048), blk, 0, stream>>>(Ee, LLp, outp, NOUT);
}

// Round 6
// 611.041 us; speedup vs baseline: 2.9561x; 1.1150x over previous
//
#include <hip/hip_runtime.h>
#include <math.h>

// NoiScaleModule: B=128, C=32(seq), S=512(d_model), EMB=256, NHEAD=8, DFF=2048
// All tensors FLOAT32. Outputs concat flat: res[2M], down_x[2M], fa[2M], up[2M]
//
// Simplifications:
//  - 'high' freq branch dead (xcat == low); h1/hb1 unused.
//  - rfft folded into low-projection (Wa); irfft+linear_change folded (Wm).
//  - GEMMs on bf16 MFMA 16x16x32, 64x128 tiles (R6: TM=64 doubles block count;
//    N=512 grids were 128 blocks on 256 CUs = half-idle, OccupancyPercent 5%).
//  - lin2 (K=2048) split-K=2, deterministic dual-buffer + 3-input add_ln.
//  - freq GEMMs + r-qkv: fused hi/lo bf16 3-product MFMA (f32-grade).
//  - cattn: 2 blocks/batch, LDS-resident X (XOR swizzle), emits hi/lo bf16.

#define NROW 4096
#define NOUT 2097152

typedef __attribute__((ext_vector_type(8))) short short8;
typedef __attribute__((ext_vector_type(4))) float floatx4;

__device__ __forceinline__ unsigned short f2bf(float f) {
    union { float f; unsigned u; } v; v.f = f;
    return (unsigned short)((v.u + 0x7fffu + ((v.u >> 16) & 1u)) >> 16);
}
__device__ __forceinline__ float bf2f(unsigned short h) {
    union { unsigned u; float f; } v; v.u = ((unsigned)h) << 16;
    return v.f;
}
__device__ __forceinline__ float ldv(const float* p, size_t i) { return p[i]; }
__device__ __forceinline__ float ldv(const unsigned short* p, size_t i) { return bf2f(p[i]); }

__device__ __forceinline__ void gload16(const unsigned short* g, unsigned short* l) {
    __builtin_amdgcn_global_load_lds((const __attribute__((address_space(1))) void*)g,
                                     (__attribute__((address_space(3))) void*)l, 16, 0, 0);
}

// ---------------- prep: cos/sin tables tab[n][k], n<512, k<256 ----------------
__global__ __launch_bounds__(256) void tab_kernel(float* __restrict__ tabC, float* __restrict__ tabS)
{
    int n = blockIdx.x, k = threadIdx.x;
    int m = (n * k) & 511;
    float th = (float)m * 0.01227184630308513f;  // 2*pi/512
    float s, c; sincosf(th, &s, &c);
    tabC[n * 256 + k] = c;
    tabS[n * 256 + k] = s;
}

__global__ __launch_bounds__(256) void wa_kernel(const float* __restrict__ l1_re, const float* __restrict__ l1_im,
                                                 const float* __restrict__ tabC, const float* __restrict__ tabS,
                                                 float* __restrict__ Wa)
{
    int n  = blockIdx.x;
    int ep = blockIdx.y * 256 + threadIdx.x;
    const float inv = 0.04419417382415922f;  // 1/sqrt(512)
    float acc = 0.f;
    if (ep < 256) {
        for (int k = 0; k < 128; ++k) {
            float c = tabC[n * 256 + k], s = tabS[n * 256 + k];
            acc += c * l1_re[k * 256 + ep] + s * l1_im[k * 256 + ep];
        }
    } else {
        int e = ep - 256;
        for (int k = 0; k < 128; ++k) {
            float c = tabC[n * 256 + k], s = tabS[n * 256 + k];
            acc += c * l1_im[k * 256 + e] - s * l1_re[k * 256 + e];
        }
    }
    Wa[(size_t)ep * 512 + n] = acc * inv;
}

__global__ __launch_bounds__(256) void wm_kernel(const float* __restrict__ lc_w,
                                                 const float* __restrict__ tabC, const float* __restrict__ tabS,
                                                 float* __restrict__ Wm)
{
    int s  = blockIdx.x;
    int kk = blockIdx.y * 256 + threadIdx.x;
    const float inv = 0.04419417382415922f;
    float acc = 0.f;
    if (kk < 256) {
        int k = kk;
        for (int n = 0; n < 512; ++n) acc += tabC[n * 256 + k] * lc_w[s * 512 + n];
        acc *= (k == 0) ? inv : 2.f * inv;
    } else {
        int k = kk - 256;
        if (k == 0) acc = 0.f;
        else {
            for (int n = 0; n < 512; ++n) acc += tabS[n * 256 + k] * lc_w[s * 512 + n];
            acc *= -2.f * inv;
        }
    }
    Wm[(size_t)s * 512 + kk] = acc;
}

// LB[0:512] = [lb1_re|lb1_im]
__global__ __launch_bounds__(256) void lbpack_kernel(const float* __restrict__ re, const float* __restrict__ im,
                                                     float* __restrict__ out)
{
    int i = threadIdx.x + blockIdx.x * 256;  // 0..511
    if (i < 512) out[i] = (i < 256) ? re[i] : im[i - 256];
}

// convert all 10 weight matrices to bf16 into one arena
__global__ __launch_bounds__(256) void wcvt_kernel(
    const float* s0, const float* s1, const float* s2, const float* s3, const float* s4,
    const float* s5, const float* s6, const float* s7, const float* s8, const float* s9,
    unsigned short* __restrict__ o)
{
    int i = blockIdx.x * 256 + threadIdx.x;
    if (i >= 6815744) return;
    const float* s; int off;
    if (i < 3145728) {
        if (i < 1048576) { if (i < 786432) { s = s0; off = 0; } else { s = s1; off = 786432; } }
        else             { if (i < 2097152) { s = s2; off = 1048576; } else { s = s3; off = 2097152; } }
    } else {
        if (i < 5242880) {
            if (i < 3932160) { s = s4; off = 3145728; }
            else if (i < 4194304) { s = s5; off = 3932160; }
            else { s = s6; off = 4194304; }
        } else {
            if (i < 6291456) { s = s7; off = 5242880; }
            else if (i < 6553600) { s = s8; off = 6291456; }
            else { s = s9; off = 6553600; }
        }
    }
    o[i] = f2bf(s[i - off]);
}

__global__ __launch_bounds__(256) void cvt_hilo_kernel(const float* __restrict__ a, unsigned short* __restrict__ hi,
                                                       unsigned short* __restrict__ lo, int n)
{
    for (int i = blockIdx.x * 256 + threadIdx.x; i < n; i += gridDim.x * 256) {
        unsigned short h = f2bf(a[i]);
        hi[i] = h;
        lo[i] = f2bf(a[i] - bf2f(h));
    }
}
__global__ __launch_bounds__(256) void cvt_lo_kernel(const float* __restrict__ a, const unsigned short* __restrict__ hi,
                                                     unsigned short* __restrict__ lo, int n)
{
    for (int i = blockIdx.x * 256 + threadIdx.x; i < n; i += gridDim.x * 256)
        lo[i] = f2bf(a[i] - bf2f(hi[i]));
}

// ---------------- MFMA GEMM: C[M,N] = A[M,K](bf16) @ W[N,K](bf16)^T + bias ----------------
// TM x 128 tile, BK=32, 4 waves (2x2), each wave (TM/2)x64 via (TM/32)x4 mfma_16x16x32_bf16.
// SPLIT2: gridDim.z=2, z=0 -> Cf (+bias), z=1 -> Cf2 (raw); consumer sums.
template <int TM, int ACT, int WF, int WBF, int SPLIT2>
__global__ __launch_bounds__(256) void gemm_mfma(
    const unsigned short* __restrict__ A, const unsigned short* __restrict__ W,
    const float* __restrict__ bias, float* __restrict__ Cf, float* __restrict__ Cf2,
    unsigned short* __restrict__ Cb, int N, int K)
{
    constexpr int MI = TM / 32;      // a-frags per wave
    constexpr int AR = TM / 4;       // A rows staged per wave
    __shared__ unsigned short As[TM * 32];
    __shared__ unsigned short Bs[128 * 32];
    const int tid = threadIdx.x;
    const int wave = tid >> 6, lane = tid & 63;
    const int m0 = blockIdx.y * TM, n0 = blockIdx.x * 128;
    const int z = SPLIT2 ? blockIdx.z : 0;
    const int kLen = SPLIT2 ? (K >> 1) : K;
    const size_t kOff = (size_t)z * kLen;
    const int sr = lane >> 2, sc = (lane & 3) * 8;
    const unsigned short* aS = A + (size_t)(m0 + wave * AR + sr) * K + kOff + sc;
    const unsigned short* wS = W + (size_t)(n0 + wave * 32 + sr) * K + kOff + sc;
    const int wm = (wave >> 1) * (TM / 2), wn = (wave & 1) * 64;
    const int fr = lane & 15, fko = (lane >> 4) * 8;

    floatx4 acc[MI][4];
#pragma unroll
    for (int i = 0; i < MI; ++i)
#pragma unroll
        for (int j = 0; j < 4; ++j) acc[i][j] = (floatx4){0.f, 0.f, 0.f, 0.f};

    for (int k0 = 0; k0 < kLen; k0 += 32) {
#pragma unroll
        for (int c = 0; c < AR / 16; ++c)
            gload16(aS + (size_t)(16 * c) * K + k0, &As[(wave * AR + 16 * c) * 32]);
#pragma unroll
        for (int c = 0; c < 2; ++c)
            gload16(wS + (size_t)(16 * c) * K + k0, &Bs[(wave * 32 + 16 * c) * 32]);
        __syncthreads();
        short8 af[MI], bfr[4];
#pragma unroll
        for (int i = 0; i < MI; ++i) af[i] = *(const short8*)&As[(wm + i * 16 + fr) * 32 + fko];
#pragma unroll
        for (int j = 0; j < 4; ++j) bfr[j] = *(const short8*)&Bs[(wn + j * 16 + fr) * 32 + fko];
#pragma unroll
        for (int i = 0; i < MI; ++i)
#pragma unroll
            for (int j = 0; j < 4; ++j)
                acc[i][j] = __builtin_amdgcn_mfma_f32_16x16x32_bf16(af[i], bfr[j], acc[i][j], 0, 0, 0);
        __syncthreads();
    }
    const int r0 = m0 + wm + (lane >> 4) * 4;
#pragma unroll
    for (int i = 0; i < MI; ++i) {
#pragma unroll
        for (int j = 0; j < 4; ++j) {
            int n = n0 + wn + j * 16 + fr;
            float bv = (z == 0) ? bias[n] : 0.f;
#pragma unroll
            for (int r = 0; r < 4; ++r) {
                int m = r0 + i * 16 + r;
                size_t idx = (size_t)m * N + n;
                float v = acc[i][j][r] + bv;
                if (ACT) v = fmaxf(v, 0.f);
                if (SPLIT2) {
                    if (z == 0) Cf[idx] = v; else Cf2[idx] = v;
                } else {
                    if (WF) Cf[idx] = v;
                    if (WBF) Cb[idx] = f2bf(v);
                }
            }
        }
    }
}

// ---------------- fused hi/lo 3-product MFMA GEMM: C = (Ah+Al)@(Wh+Wl)^T + bias ----------
// acc += Al*Wh + Ah*Wl + Ah*Wh (drops lo*lo). WCOPY: also copy result to Ccopy.
template <int TM, int ACT, int WCOPY>
__global__ __launch_bounds__(256) void gemm_mfma3(
    const unsigned short* __restrict__ Ah, const unsigned short* __restrict__ Al,
    const unsigned short* __restrict__ Wh, const unsigned short* __restrict__ Wl,
    const float* __restrict__ bias, float* __restrict__ Cf, float* __restrict__ Ccopy,
    int N, int K)
{
    constexpr int MI = TM / 32;
    constexpr int AR = TM / 4;
    __shared__ unsigned short Ash[TM * 32];
    __shared__ unsigned short Asl[TM * 32];
    __shared__ unsigned short Bsh[128 * 32];
    __shared__ unsigned short Bsl[128 * 32];
    const int tid = threadIdx.x;
    const int wave = tid >> 6, lane = tid & 63;
    const int m0 = blockIdx.y * TM, n0 = blockIdx.x * 128;
    const int sr = lane >> 2, sc = (lane & 3) * 8;
    const size_t aoff = (size_t)(m0 + wave * AR + sr) * K + sc;
    const size_t woff = (size_t)(n0 + wave * 32 + sr) * K + sc;
    const int wm = (wave >> 1) * (TM / 2), wn = (wave & 1) * 64;
    const int fr = lane & 15, fko = (lane >> 4) * 8;

    floatx4 acc[MI][4];
#pragma unroll
    for (int i = 0; i < MI; ++i)
#pragma unroll
        for (int j = 0; j < 4; ++j) acc[i][j] = (floatx4){0.f, 0.f, 0.f, 0.f};

    for (int k0 = 0; k0 < K; k0 += 32) {
#pragma unroll
        for (int c = 0; c < AR / 16; ++c) {
            gload16(Ah + aoff + (size_t)(16 * c) * K + k0, &Ash[(wave * AR + 16 * c) * 32]);
            gload16(Al + aoff + (size_t)(16 * c) * K + k0, &Asl[(wave * AR + 16 * c) * 32]);
        }
#pragma unroll
        for (int c = 0; c < 2; ++c) {
            gload16(Wh + woff + (size_t)(16 * c) * K + k0, &Bsh[(wave * 32 + 16 * c) * 32]);
            gload16(Wl + woff + (size_t)(16 * c) * K + k0, &Bsl[(wave * 32 + 16 * c) * 32]);
        }
        __syncthreads();
        short8 ah[MI], al[MI], bh[4], bl[4];
#pragma unroll
        for (int i = 0; i < MI; ++i) {
            ah[i] = *(const short8*)&Ash[(wm + i * 16 + fr) * 32 + fko];
            al[i] = *(const short8*)&Asl[(wm + i * 16 + fr) * 32 + fko];
        }
#pragma unroll
        for (int j = 0; j < 4; ++j) {
            bh[j] = *(const short8*)&Bsh[(wn + j * 16 + fr) * 32 + fko];
            bl[j] = *(const short8*)&Bsl[(wn + j * 16 + fr) * 32 + fko];
        }
#pragma unroll
        for (int i = 0; i < MI; ++i)
#pragma unroll
            for (int j = 0; j < 4; ++j) {
                acc[i][j] = __builtin_amdgcn_mfma_f32_16x16x32_bf16(al[i], bh[j], acc[i][j], 0, 0, 0);
                acc[i][j] = __builtin_amdgcn_mfma_f32_16x16x32_bf16(ah[i], bl[j], acc[i][j], 0, 0, 0);
                acc[i][j] = __builtin_amdgcn_mfma_f32_16x16x32_bf16(ah[i], bh[j], acc[i][j], 0, 0, 0);
            }
        __syncthreads();
    }
    const int r0 = m0 + wm + (lane >> 4) * 4;
#pragma unroll
    for (int i = 0; i < MI; ++i) {
#pragma unroll
        for (int j = 0; j < 4; ++j) {
            int n = n0 + wn + j * 16 + fr;
            float bv = bias[n];
#pragma unroll
            for (int r = 0; r < 4; ++r) {
                int m = r0 + i * 16 + r;
                size_t idx = (size_t)m * N + n;
                float v = acc[i][j][r] + bv;
                if (ACT) v = fmaxf(v, 0.f);
                Cf[idx] = v;
                if (WCOPY) Ccopy[idx] = v;
            }
        }
    }
}

// ---------------- TEL attention: one block per (batch, head); bf16 out ----------------
template <typename T>
__global__ __launch_bounds__(256) void attn_kernel(const T* __restrict__ qkv, unsigned short* __restrict__ outb)
{
    const int b = blockIdx.x >> 3;
    const int h = blockIdx.x & 7;
    __shared__ float qs[32][65], ks[32][65], vs[32][65];
    __shared__ float ps[32][33];
    const int tid = threadIdx.x;
    for (int i = tid; i < 2048; i += 256) {
        int s = i >> 6, d = i & 63;
        size_t base = ((size_t)(b * 32 + s)) * 1536 + h * 64 + d;
        qs[s][d] = ldv(qkv, base);
        ks[s][d] = ldv(qkv, base + 512);
        vs[s][d] = ldv(qkv, base + 1024);
    }
    __syncthreads();
    for (int i = tid; i < 1024; i += 256) {
        int si = i >> 5, sj = i & 31;
        float acc = 0.f;
#pragma unroll 8
        for (int d = 0; d < 64; ++d) acc += qs[si][d] * ks[sj][d];
        ps[si][sj] = acc * 0.125f;
    }
    __syncthreads();
    if (tid < 32) {
        float mx = -1e30f;
        for (int j = 0; j < 32; ++j) mx = fmaxf(mx, ps[tid][j]);
        float sum = 0.f;
        for (int j = 0; j < 32; ++j) { float e = __expf(ps[tid][j] - mx); ps[tid][j] = e; sum += e; }
        float inv = 1.f / sum;
        for (int j = 0; j < 32; ++j) ps[tid][j] *= inv;
    }
    __syncthreads();
    for (int i = tid; i < 2048; i += 256) {
        int s = i >> 6, d = i & 63;
        float acc = 0.f;
#pragma unroll 8
        for (int k = 0; k < 32; ++k) acc += ps[s][k] * vs[k][d];
        outb[((size_t)(b * 32 + s)) * 512 + h * 64 + d] = f2bf(acc);
    }
}

// ---------------- complex self-attention: LDS-resident, grid (128 batch, 2 half) ----------
__global__ __launch_bounds__(256) void cattn2_kernel(const float* __restrict__ LL,
                                                     unsigned short* __restrict__ outHi,
                                                     unsigned short* __restrict__ outLo)
{
    extern __shared__ float Xs[];
    __shared__ float Pr[16][33], Pi[16][33];
    const int b = blockIdx.x, half = blockIdx.y;
    const int tid = threadIdx.x;
    const float* base = LL + (size_t)b * 16384;
    for (int i = tid; i < 16384; i += 256) {
        int c = i >> 9, e = i & 511;
        Xs[e * 32 + ((c ^ e) & 31)] = base[i];
    }
    __syncthreads();
    {
        const int li0 = tid >> 5, li1 = li0 + 8;
        const int ci0 = half * 16 + li0, ci1 = half * 16 + li1;
        const int ck = tid & 31;
        float ar0 = 0.f, ai0 = 0.f, ar1 = 0.f, ai1 = 0.f;
        for (int er = 0; er < 256; ++er) {
            const int sw = er & 31;
            float yr = Xs[er * 32 + ((ck ^ sw) & 31)];
            float yi = Xs[(er + 256) * 32 + ((ck ^ sw) & 31)];
            float xr0 = Xs[er * 32 + ((ci0 ^ sw) & 31)];
            float xi0 = Xs[(er + 256) * 32 + ((ci0 ^ sw) & 31)];
            float xr1 = Xs[er * 32 + ((ci1 ^ sw) & 31)];
            float xi1 = Xs[(er + 256) * 32 + ((ci1 ^ sw) & 31)];
            ar0 += xr0 * yr - xi0 * yi;  ai0 += xr0 * yi + xi0 * yr;
            ar1 += xr1 * yr - xi1 * yi;  ai1 += xr1 * yi + xi1 * yr;
        }
        Pr[li0][ck] = ar0 * 0.0625f;  Pi[li0][ck] = ai0 * 0.0625f;
        Pr[li1][ck] = ar1 * 0.0625f;  Pi[li1][ck] = ai1 * 0.0625f;
    }
    __syncthreads();
    if (tid < 32) {
        int r = tid & 15;
        float (*P)[33] = (tid < 16) ? Pr : Pi;
        float mx = -1e30f;
        for (int j = 0; j < 32; ++j) mx = fmaxf(mx, P[r][j]);
        float s = 0.f;
        for (int j = 0; j < 32; ++j) { float e = __expf(P[r][j] - mx); P[r][j] = e; s += e; }
        float inv = 1.f / s;
        for (int j = 0; j < 32; ++j) P[r][j] *= inv;
    }
    __syncthreads();
    const int er = tid;
    const int sw = er & 31;
    float accr[16], acci[16];
#pragma unroll
    for (int t = 0; t < 16; ++t) { accr[t] = 0.f; acci[t] = 0.f; }
    for (int k = 0; k < 32; ++k) {
        float yr = Xs[er * 32 + ((k ^ sw) & 31)];
        float yi = Xs[(er + 256) * 32 + ((k ^ sw) & 31)];
#pragma unroll
        for (int t = 0; t < 16; ++t) {
            float pr = Pr[t][k], pi = Pi[t][k];
            accr[t] += pr * yr - pi * yi;
            acci[t] += pr * yi + pi * yr;
        }
    }
#pragma unroll
    for (int t = 0; t < 16; ++t) {
        int c = half * 16 + t;
        float vr = Xs[er * 32 + ((c ^ sw) & 31)] + accr[t];
        float vi = Xs[(er + 256) * 32 + ((c ^ sw) & 31)] + acci[t];
        size_t ir = (size_t)b * 16384 + (size_t)c * 512 + er;
        unsigned short hr = f2bf(vr), hi2 = f2bf(vi);
        outHi[ir] = hr;        outLo[ir] = f2bf(vr - bf2f(hr));
        outHi[ir + 256] = hi2; outLo[ir + 256] = f2bf(vi - bf2f(hi2));
    }
}

// ---------------- residual add + LayerNorm (512), optional 2nd summand + bf16 copy ------
template <int WBF, int Y2>
__global__ __launch_bounds__(256) void add_ln_kernel(const float* __restrict__ resid, const float* __restrict__ y,
                                                     const float* __restrict__ y2,
                                                     const float* __restrict__ w, const float* __restrict__ b,
                                                     float* __restrict__ outf, unsigned short* __restrict__ outb)
{
    const int row = blockIdx.x;
    const int tid = threadIdx.x;
    const size_t base = (size_t)row * 512;
    float v0 = resid[base + tid] + y[base + tid];
    float v1 = resid[base + 256 + tid] + y[base + 256 + tid];
    if (Y2) { v0 += y2[base + tid]; v1 += y2[base + 256 + tid]; }
    float s = v0 + v1, q = v0 * v0 + v1 * v1;
    for (int off = 32; off; off >>= 1) { s += __shfl_down(s, off); q += __shfl_down(q, off); }
    __shared__ float sw[4], qw[4], ms, is;
    int wid = tid >> 6, lane = tid & 63;
    if (lane == 0) { sw[wid] = s; qw[wid] = q; }
    __syncthreads();
    if (tid == 0) {
        float S = sw[0] + sw[1] + sw[2] + sw[3];
        float Q = qw[0] + qw[1] + qw[2] + qw[3];
        float m = S * (1.f / 512.f);
        ms = m;
        is = rsqrtf(Q * (1.f / 512.f) - m * m + 1e-5f);
    }
    __syncthreads();
    float m = ms, inv = is;
    float o0 = (v0 - m) * inv * w[tid] + b[tid];
    float o1 = (v1 - m) * inv * w[256 + tid] + b[256 + tid];
    outf[base + tid] = o0;
    outf[base + 256 + tid] = o1;
    if (WBF) { outb[base + tid] = f2bf(o0); outb[base + 256 + tid] = f2bf(o1); }
}

// ---------------- relu + LayerNorm over (C,S)=16384 per batch, optional final add -------
template <int ADDF>
__global__ __launch_bounds__(256) void relu_bln_kernel(const float* __restrict__ xin,
                                                       const float* __restrict__ w, const float* __restrict__ b,
                                                       const float* __restrict__ addsrc,
                                                       float* __restrict__ out)
{
    const int bb = blockIdx.x;
    const int tid = threadIdx.x;
    const float* xp = xin + (size_t)bb * 16384;
    float s = 0.f, q = 0.f;
    for (int i = tid; i < 16384; i += 256) { float v = fmaxf(xp[i], 0.f); s += v; q += v * v; }
    for (int off = 32; off; off >>= 1) { s += __shfl_down(s, off); q += __shfl_down(q, off); }
    __shared__ float sw[4], qw[4], ms, is;
    int wid = tid >> 6, lane = tid & 63;
    if (lane == 0) { sw[wid] = s; qw[wid] = q; }
    __syncthreads();
    if (tid == 0) {
        float S = sw[0] + sw[1] + sw[2] + sw[3];
        float Q = qw[0] + qw[1] + qw[2] + qw[3];
        float m = S * (1.f / 16384.f);
        ms = m;
        is = rsqrtf(Q * (1.f / 16384.f) - m * m + 1e-5f);
    }
    __syncthreads();
    float m = ms, inv = is;
    const float* ap = ADDF ? (addsrc + (size_t)bb * 16384) : nullptr;
    float* op = out + (size_t)bb * 16384;
    for (int i = tid; i < 16384; i += 256) {
        float v = fmaxf(xp[i], 0.f);
        float o = (v - m) * inv * w[i] + b[i];
        if (ADDF) o += ap[i];
        op[i] = o;
    }
}

extern "C" void kernel_launch(void* const* d_in, const int* in_sizes, int n_in,
                              void* d_out, int out_size, void* d_ws, size_t ws_size,
                              hipStream_t stream)
{
    (void)in_sizes; (void)n_in; (void)out_size; (void)ws_size;
    const float* x        = (const float*)d_in[0];
    const float* t_in_w   = (const float*)d_in[1];
    const float* t_in_b   = (const float*)d_in[2];
    const float* t_out_w  = (const float*)d_in[3];
    const float* t_out_b  = (const float*)d_in[4];
    const float* t_ln1_w  = (const float*)d_in[5];
    const float* t_ln1_b  = (const float*)d_in[6];
    const float* t_lin1_w = (const float*)d_in[7];
    const float* t_lin1_b = (const float*)d_in[8];
    const float* t_lin2_w = (const float*)d_in[9];
    const float* t_lin2_b = (const float*)d_in[10];
    const float* t_ln2_w  = (const float*)d_in[11];
    const float* t_ln2_b  = (const float*)d_in[12];
    const float* r_in_w   = (const float*)d_in[13];
    const float* r_in_b   = (const float*)d_in[14];
    const float* r_out_w  = (const float*)d_in[15];
    const float* r_out_b  = (const float*)d_in[16];
    const float* r_ln1_w  = (const float*)d_in[17];
    const float* r_ln1_b  = (const float*)d_in[18];
    const float* r_lin1_w = (const float*)d_in[19];
    const float* r_lin1_b = (const float*)d_in[20];
    const float* r_lin2_w = (const float*)d_in[21];
    const float* r_lin2_b = (const float*)d_in[22];
    const float* r_ln2_w  = (const float*)d_in[23];
    const float* r_ln2_b  = (const float*)d_in[24];
    const float* lc_w     = (const float*)d_in[25];
    const float* lc_b     = (const float*)d_in[26];
    const float* up1_w    = (const float*)d_in[27];
    const float* up1_b    = (const float*)d_in[28];
    const float* up2_w    = (const float*)d_in[29];
    const float* up2_b    = (const float*)d_in[30];
    const float* n1_w     = (const float*)d_in[31];
    const float* n1_b     = (const float*)d_in[32];
    const float* n2_w     = (const float*)d_in[33];
    const float* n2_b     = (const float*)d_in[34];
    const float* l1_re    = (const float*)d_in[35];
    const float* l1_im    = (const float*)d_in[36];
    const float* lb1_re   = (const float*)d_in[39];
    const float* lb1_im   = (const float*)d_in[40];

    float* outp = (float*)d_out;

    // ---- workspace (float offsets; total 21,774,336 f = 87.1 MB, validated size) ----
    float* WS   = (float*)d_ws;
    float* WaF  = WS + 0;          // 262144 f32 Wa; later WmH/WmL ushort
    float* WmF  = WS + 262144;     // 262144 f32 Wm
    float* LB   = WS + 524288;     // 16384 ([0:512) lb bias)
    float* BIGf = WS + 540672;     // 6291456: r-qkv f32 | f1 bf16 [0:4194304) | BbF [4194304:)
    float* Cc   = WS + 6832128;    // 2097152: x1/x1r f32; AabU ushort alias lower half
    float* Ee   = WS + 8929280;    // 2097152: tab(prep) -> lin2-t z1 partial -> x2 -> df
    float* LLp  = WS + 11026432;   // 2097152: low f32 -> rinLo alias -> lin2-r z1 partial -> x2r -> rf
    float* FAp  = WS + 13123584;   // 2097152: WaH/WaL(prep) -> fa f32
    float* U1f  = WS + 15220736;   // 1048576: ushort x_hi -> x1b -> x1rb
    float* U2f  = WS + 16269312;   // 1048576: ushort x_lo -> LL_hi -> fa_hi
    float* U3f  = WS + 17317888;   // 1048576: ushort LL_lo -> fa_lo
    float* WBf  = WS + 18366464;   // 3407872: ushort weights (6815744)

    float* BbF  = BIGf + 4194304;  // disjoint from f1 bf16 alias [0:4194304)
    float* tabC = Ee;
    float* tabS = Ee + 131072;
    unsigned short* BIGu   = (unsigned short*)BIGf;
    unsigned short* AabU   = (unsigned short*)Cc;
    unsigned short* rinLoU = (unsigned short*)LLp;            // 786432 u
    unsigned short* WaHu   = (unsigned short*)FAp;
    unsigned short* WaLu   = (unsigned short*)(FAp + 131072);
    unsigned short* WmHu   = (unsigned short*)WaF;
    unsigned short* WmLu   = (unsigned short*)(WaF + 131072);
    unsigned short* U1u    = (unsigned short*)U1f;
    unsigned short* U2u    = (unsigned short*)U2f;
    unsigned short* U3u    = (unsigned short*)U3f;
    unsigned short* WB     = (unsigned short*)WBf;

    unsigned short* w_tin  = WB + 0;        // 1536x512
    unsigned short* w_tout = WB + 786432;   // 512x512
    unsigned short* w_tl1  = WB + 1048576;  // 2048x512
    unsigned short* w_tl2  = WB + 2097152;  // 512x2048
    unsigned short* w_rin  = WB + 3145728;  // 1536x512
    unsigned short* w_rout = WB + 3932160;  // 512x512
    unsigned short* w_rl1  = WB + 4194304;  // 2048x512
    unsigned short* w_rl2  = WB + 5242880;  // 512x2048
    unsigned short* w_up1  = WB + 6291456;  // 512x512
    unsigned short* w_up2  = WB + 6553600;  // 512x512

    dim3 blk(256);

    // ---- prep ----
    tab_kernel<<<dim3(512), blk, 0, stream>>>(tabC, tabS);
    wa_kernel<<<dim3(512, 2), blk, 0, stream>>>(l1_re, l1_im, tabC, tabS, WaF);
    wm_kernel<<<dim3(512, 2), blk, 0, stream>>>(lc_w, tabC, tabS, WmF);
    cvt_hilo_kernel<<<dim3(1024), blk, 0, stream>>>(WaF, WaHu, WaLu, 262144);
    cvt_hilo_kernel<<<dim3(1024), blk, 0, stream>>>(WmF, WmHu, WmLu, 262144);
    lbpack_kernel<<<dim3(2), blk, 0, stream>>>(lb1_re, lb1_im, LB);
    wcvt_kernel<<<dim3(26624), blk, 0, stream>>>(t_in_w, t_out_w, t_lin1_w, t_lin2_w,
                                                 r_in_w, r_out_w, r_lin1_w, r_lin2_w,
                                                 up1_w, up2_w, WB);
    cvt_hilo_kernel<<<dim3(2048), blk, 0, stream>>>(x, U1u, U2u, NOUT);         // x hi/lo

    // ---- output 1: down_x = x ----
    hipMemcpyAsync(outp + NOUT, x, (size_t)NOUT * sizeof(float), hipMemcpyDeviceToDevice, stream);

    // ---- freq branch ----
    gemm_mfma3<64,1,0><<<dim3(4, 64), blk, 0, stream>>>(U1u, U2u, WaHu, WaLu, LB, LLp, nullptr, 512, 512);
    cattn2_kernel<<<dim3(128, 2), blk, 65536, stream>>>(LLp, U2u, U3u);          // LL hi/lo
    gemm_mfma3<64,0,1><<<dim3(4, 64), blk, 0, stream>>>(U2u, U3u, WmHu, WmLu, lc_b, FAp, outp + 2 * NOUT, 512, 512);
    cvt_lo_kernel<<<dim3(768), blk, 0, stream>>>(r_in_w, w_rin, rinLoU, 786432); // rin lo (LLp dead)

    // ---- t-TEL on x ----
    gemm_mfma<64,0,0,1,0><<<dim3(12, 64), blk, 0, stream>>>(U1u, w_tin, t_in_b, nullptr, nullptr, BIGu, 1536, 512);
    attn_kernel<unsigned short><<<dim3(1024), blk, 0, stream>>>(BIGu, AabU);
    gemm_mfma<64,0,1,0,0><<<dim3(4, 64), blk, 0, stream>>>(AabU, w_tout, t_out_b, BbF, nullptr, nullptr, 512, 512);
    add_ln_kernel<1,0><<<dim3(4096), blk, 0, stream>>>(x, BbF, nullptr, t_ln1_w, t_ln1_b, Cc, U1u); // x1 (+bf16)
    gemm_mfma<64,1,0,1,0><<<dim3(16, 64), blk, 0, stream>>>(U1u, w_tl1, t_lin1_b, nullptr, nullptr, BIGu, 2048, 512);
    gemm_mfma<64,0,1,0,1><<<dim3(4, 64, 2), blk, 0, stream>>>(BIGu, w_tl2, t_lin2_b, BbF, Ee, nullptr, 512, 2048);
    add_ln_kernel<0,1><<<dim3(4096), blk, 0, stream>>>(Cc, BbF, Ee, t_ln2_w, t_ln2_b, Ee, nullptr);  // x2
    relu_bln_kernel<0><<<dim3(128), blk, 0, stream>>>(Ee, n1_w, n1_b, nullptr, Ee);                  // df

    // fa -> hi/lo bf16 (U2/U3; LL hi/lo dead after Wm-GEMM)
    cvt_hilo_kernel<<<dim3(2048), blk, 0, stream>>>(FAp, U2u, U3u, NOUT);

    // ---- upsample ----
    gemm_mfma<64,0,0,1,0><<<dim3(4, 64), blk, 0, stream>>>(U2u, w_up1, up1_b, nullptr, nullptr, AabU, 512, 512);
    gemm_mfma<64,0,1,0,0><<<dim3(4, 64), blk, 0, stream>>>(AabU, w_up2, up2_b, outp + 3 * NOUT, nullptr, nullptr, 512, 512);

    // ---- r-TEL on fa (fused hi/lo qkv) ----
    gemm_mfma3<64,0,0><<<dim3(12, 64), blk, 0, stream>>>(U2u, U3u, w_rin, rinLoU, r_in_b, BIGf, nullptr, 1536, 512);
    attn_kernel<float><<<dim3(1024), blk, 0, stream>>>(BIGf, AabU);
    gemm_mfma<64,0,1,0,0><<<dim3(4, 64), blk, 0, stream>>>(AabU, w_rout, r_out_b, BbF, nullptr, nullptr, 512, 512);
    add_ln_kernel<1,0><<<dim3(4096), blk, 0, stream>>>(FAp, BbF, nullptr, r_ln1_w, r_ln1_b, Cc, U1u); // x1r (+bf16)
    gemm_mfma<64,1,0,1,0><<<dim3(16, 64), blk, 0, stream>>>(U1u, w_rl1, r_lin1_b, nullptr, nullptr, BIGu, 2048, 512);
    gemm_mfma<64,0,1,0,1><<<dim3(4, 64, 2), blk, 0, stream>>>(BIGu, w_rl2, r_lin2_b, BbF, LLp, nullptr, 512, 2048);
    add_ln_kernel<0,1><<<dim3(4096), blk, 0, stream>>>(Cc, BbF, LLp, r_ln2_w, r_ln2_b, LLp, nullptr); // x2r
    relu_bln_kernel<1><<<dim3(128), blk, 0, stream>>>(LLp, n2_w, n2_b, Ee, outp);                     // res = rf + df
}

// Round 7
// 589.398 us; speedup vs baseline: 3.0647x; 1.0367x over previous
//
#include <hip/hip_runtime.h>
#include <math.h>

// NoiScaleModule: B=128, C=32(seq), S=512(d_model), EMB=256, NHEAD=8, DFF=2048
// All tensors FLOAT32. Outputs concat flat: res[2M], down_x[2M], fa[2M], up[2M]
//
// R7: TN=64 + split-K=2 for all N=512 GEMMs (2-4 blocks/CU); branch order
// freq -> up -> r-TEL -> t-TEL so Wm-GEMM epilogue emits fa hi/lo into dead Cc
// arena (kills cvt_hilo dispatch); xsplit fuses x hi/lo + down_x copy.

#define NROW 4096
#define NOUT 2097152

typedef __attribute__((ext_vector_type(8))) short short8;
typedef __attribute__((ext_vector_type(4))) float floatx4;

__device__ __forceinline__ unsigned short f2bf(float f) {
    union { float f; unsigned u; } v; v.f = f;
    return (unsigned short)((v.u + 0x7fffu + ((v.u >> 16) & 1u)) >> 16);
}
__device__ __forceinline__ float bf2f(unsigned short h) {
    union { unsigned u; float f; } v; v.u = ((unsigned)h) << 16;
    return v.f;
}
__device__ __forceinline__ float ldv(const float* p, size_t i) { return p[i]; }
__device__ __forceinline__ float ldv(const unsigned short* p, size_t i) { return bf2f(p[i]); }

__device__ __forceinline__ void gload16(const unsigned short* g, unsigned short* l) {
    __builtin_amdgcn_global_load_lds((const __attribute__((address_space(1))) void*)g,
                                     (__attribute__((address_space(3))) void*)l, 16, 0, 0);
}

// ---------------- prep: cos/sin tables tab[n][k], n<512, k<256 ----------------
__global__ __launch_bounds__(256) void tab_kernel(float* __restrict__ tabC, float* __restrict__ tabS)
{
    int n = blockIdx.x, k = threadIdx.x;
    int m = (n * k) & 511;
    float th = (float)m * 0.01227184630308513f;  // 2*pi/512
    float s, c; sincosf(th, &s, &c);
    tabC[n * 256 + k] = c;
    tabS[n * 256 + k] = s;
}

__global__ __launch_bounds__(256) void wa_kernel(const float* __restrict__ l1_re, const float* __restrict__ l1_im,
                                                 const float* __restrict__ tabC, const float* __restrict__ tabS,
                                                 float* __restrict__ Wa)
{
    int n  = blockIdx.x;
    int ep = blockIdx.y * 256 + threadIdx.x;
    const float inv = 0.04419417382415922f;  // 1/sqrt(512)
    float acc = 0.f;
    if (ep < 256) {
        for (int k = 0; k < 128; ++k) {
            float c = tabC[n * 256 + k], s = tabS[n * 256 + k];
            acc += c * l1_re[k * 256 + ep] + s * l1_im[k * 256 + ep];
        }
    } else {
        int e = ep - 256;
        for (int k = 0; k < 128; ++k) {
            float c = tabC[n * 256 + k], s = tabS[n * 256 + k];
            acc += c * l1_im[k * 256 + e] - s * l1_re[k * 256 + e];
        }
    }
    Wa[(size_t)ep * 512 + n] = acc * inv;
}

__global__ __launch_bounds__(256) void wm_kernel(const float* __restrict__ lc_w,
                                                 const float* __restrict__ tabC, const float* __restrict__ tabS,
                                                 float* __restrict__ Wm)
{
    __shared__ float lw[512];
    int s  = blockIdx.x;
    int kk = blockIdx.y * 256 + threadIdx.x;
    for (int i = threadIdx.x; i < 512; i += 256) lw[i] = lc_w[s * 512 + i];
    __syncthreads();
    const float inv = 0.04419417382415922f;
    float acc = 0.f;
    if (kk < 256) {
        int k = kk;
        for (int n = 0; n < 512; ++n) acc += tabC[n * 256 + k] * lw[n];
        acc *= (k == 0) ? inv : 2.f * inv;
    } else {
        int k = kk - 256;
        if (k == 0) acc = 0.f;
        else {
            for (int n = 0; n < 512; ++n) acc += tabS[n * 256 + k] * lw[n];
            acc *= -2.f * inv;
        }
    }
    Wm[(size_t)s * 512 + kk] = acc;
}

// LB[0:512] = [lb1_re|lb1_im]
__global__ __launch_bounds__(256) void lbpack_kernel(const float* __restrict__ re, const float* __restrict__ im,
                                                     float* __restrict__ out)
{
    int i = threadIdx.x + blockIdx.x * 256;
    if (i < 512) out[i] = (i < 256) ? re[i] : im[i - 256];
}

// convert all 10 weight matrices to bf16 into one arena
__global__ __launch_bounds__(256) void wcvt_kernel(
    const float* s0, const float* s1, const float* s2, const float* s3, const float* s4,
    const float* s5, const float* s6, const float* s7, const float* s8, const float* s9,
    unsigned short* __restrict__ o)
{
    int i = blockIdx.x * 256 + threadIdx.x;
    if (i >= 6815744) return;
    const float* s; int off;
    if (i < 3145728) {
        if (i < 1048576) { if (i < 786432) { s = s0; off = 0; } else { s = s1; off = 786432; } }
        else             { if (i < 2097152) { s = s2; off = 1048576; } else { s = s3; off = 2097152; } }
    } else {
        if (i < 5242880) {
            if (i < 3932160) { s = s4; off = 3145728; }
            else if (i < 4194304) { s = s5; off = 3932160; }
            else { s = s6; off = 4194304; }
        } else {
            if (i < 6291456) { s = s7; off = 5242880; }
            else if (i < 6553600) { s = s8; off = 6291456; }
            else { s = s9; off = 6553600; }
        }
    }
    o[i] = f2bf(s[i - off]);
}

__global__ __launch_bounds__(256) void cvt_hilo_kernel(const float* __restrict__ a, unsigned short* __restrict__ hi,
                                                       unsigned short* __restrict__ lo, int n)
{
    for (int i = blockIdx.x * 256 + threadIdx.x; i < n; i += gridDim.x * 256) {
        unsigned short h = f2bf(a[i]);
        hi[i] = h;
        lo[i] = f2bf(a[i] - bf2f(h));
    }
}
__global__ __launch_bounds__(256) void cvt_lo_kernel(const float* __restrict__ a, const unsigned short* __restrict__ hi,
                                                     unsigned short* __restrict__ lo, int n)
{
    for (int i = blockIdx.x * 256 + threadIdx.x; i < n; i += gridDim.x * 256)
        lo[i] = f2bf(a[i] - bf2f(hi[i]));
}

// x -> hi/lo bf16 + f32 copy (down_x output)
__global__ __launch_bounds__(256) void xsplit_kernel(const float* __restrict__ a, unsigned short* __restrict__ hi,
                                                     unsigned short* __restrict__ lo, float* __restrict__ cp, int n)
{
    for (int i = blockIdx.x * 256 + threadIdx.x; i < n; i += gridDim.x * 256) {
        float v = a[i];
        unsigned short h = f2bf(v);
        hi[i] = h;
        lo[i] = f2bf(v - bf2f(h));
        cp[i] = v;
    }
}

// ---------------- MFMA GEMM: C[M,N] = A[M,K](bf16) @ W[N,K](bf16)^T + bias ----------------
// TM x TN tile, BK=32, 4 waves (2x2). SPLIT2: z=0 -> Cf(+bias), z=1 -> Cf2 (raw).
template <int TM, int TN, int ACT, int WF, int WBF, int SPLIT2>
__global__ __launch_bounds__(256) void gemm_mfma(
    const unsigned short* __restrict__ A, const unsigned short* __restrict__ W,
    const float* __restrict__ bias, float* __restrict__ Cf, float* __restrict__ Cf2,
    unsigned short* __restrict__ Cb, int N, int K)
{
    constexpr int MI = TM / 32, NJ = TN / 32;
    constexpr int ARW = TM / 4, BRW = TN / 4;
    __shared__ unsigned short As[TM * 32];
    __shared__ unsigned short Bs[TN * 32];
    const int tid = threadIdx.x;
    const int wave = tid >> 6, lane = tid & 63;
    const int m0 = blockIdx.y * TM, n0 = blockIdx.x * TN;
    const int z = SPLIT2 ? blockIdx.z : 0;
    const int kLen = SPLIT2 ? (K >> 1) : K;
    const size_t kOff = (size_t)z * kLen;
    const int sr = lane >> 2, sc = (lane & 3) * 8;
    const unsigned short* aS = A + (size_t)(m0 + wave * ARW + sr) * K + kOff + sc;
    const unsigned short* wS = W + (size_t)(n0 + wave * BRW + sr) * K + kOff + sc;
    const int wm = (wave >> 1) * (TM / 2), wn = (wave & 1) * (TN / 2);
    const int fr = lane & 15, fko = (lane >> 4) * 8;

    floatx4 acc[MI][NJ];
#pragma unroll
    for (int i = 0; i < MI; ++i)
#pragma unroll
        for (int j = 0; j < NJ; ++j) acc[i][j] = (floatx4){0.f, 0.f, 0.f, 0.f};

    for (int k0 = 0; k0 < kLen; k0 += 32) {
#pragma unroll
        for (int c = 0; c < ARW / 16; ++c)
            gload16(aS + (size_t)(16 * c) * K + k0, &As[(wave * ARW + 16 * c) * 32]);
#pragma unroll
        for (int c = 0; c < BRW / 16; ++c)
            gload16(wS + (size_t)(16 * c) * K + k0, &Bs[(wave * BRW + 16 * c) * 32]);
        __syncthreads();
        short8 af[MI], bfr[NJ];
#pragma unroll
        for (int i = 0; i < MI; ++i) af[i] = *(const short8*)&As[(wm + i * 16 + fr) * 32 + fko];
#pragma unroll
        for (int j = 0; j < NJ; ++j) bfr[j] = *(const short8*)&Bs[(wn + j * 16 + fr) * 32 + fko];
#pragma unroll
        for (int i = 0; i < MI; ++i)
#pragma unroll
            for (int j = 0; j < NJ; ++j)
                acc[i][j] = __builtin_amdgcn_mfma_f32_16x16x32_bf16(af[i], bfr[j], acc[i][j], 0, 0, 0);
        __syncthreads();
    }
    const int r0 = m0 + wm + (lane >> 4) * 4;
#pragma unroll
    for (int i = 0; i < MI; ++i) {
#pragma unroll
        for (int j = 0; j < NJ; ++j) {
            int n = n0 + wn + j * 16 + fr;
            float bv = (z == 0) ? bias[n] : 0.f;
#pragma unroll
            for (int r = 0; r < 4; ++r) {
                int m = r0 + i * 16 + r;
                size_t idx = (size_t)m * N + n;
                float v = acc[i][j][r] + bv;
                if (ACT) v = fmaxf(v, 0.f);
                if (SPLIT2) {
                    if (z == 0) Cf[idx] = v; else Cf2[idx] = v;
                } else {
                    if (WF) Cf[idx] = v;
                    if (WBF) Cb[idx] = f2bf(v);
                }
            }
        }
    }
}

// ---------------- fused hi/lo 3-product MFMA GEMM: C = (Ah+Al)@(Wh+Wl)^T + bias ----------
// acc += Al*Wh + Ah*Wl + Ah*Wh (drops lo*lo). WCOPY: also copy to Ccopy. WHILO: emit hi/lo bf16.
template <int TM, int TN, int ACT, int WCOPY, int WHILO>
__global__ __launch_bounds__(256) void gemm_mfma3(
    const unsigned short* __restrict__ Ah, const unsigned short* __restrict__ Al,
    const unsigned short* __restrict__ Wh, const unsigned short* __restrict__ Wl,
    const float* __restrict__ bias, float* __restrict__ Cf, float* __restrict__ Ccopy,
    unsigned short* __restrict__ Hh, unsigned short* __restrict__ Hl, int N, int K)
{
    constexpr int MI = TM / 32, NJ = TN / 32;
    constexpr int ARW = TM / 4, BRW = TN / 4;
    __shared__ unsigned short Ash[TM * 32];
    __shared__ unsigned short Asl[TM * 32];
    __shared__ unsigned short Bsh[TN * 32];
    __shared__ unsigned short Bsl[TN * 32];
    const int tid = threadIdx.x;
    const int wave = tid >> 6, lane = tid & 63;
    const int m0 = blockIdx.y * TM, n0 = blockIdx.x * TN;
    const int sr = lane >> 2, sc = (lane & 3) * 8;
    const size_t aoff = (size_t)(m0 + wave * ARW + sr) * K + sc;
    const size_t woff = (size_t)(n0 + wave * BRW + sr) * K + sc;
    const int wm = (wave >> 1) * (TM / 2), wn = (wave & 1) * (TN / 2);
    const int fr = lane & 15, fko = (lane >> 4) * 8;

    floatx4 acc[MI][NJ];
#pragma unroll
    for (int i = 0; i < MI; ++i)
#pragma unroll
        for (int j = 0; j < NJ; ++j) acc[i][j] = (floatx4){0.f, 0.f, 0.f, 0.f};

    for (int k0 = 0; k0 < K; k0 += 32) {
#pragma unroll
        for (int c = 0; c < ARW / 16; ++c) {
            gload16(Ah + aoff + (size_t)(16 * c) * K + k0, &Ash[(wave * ARW + 16 * c) * 32]);
            gload16(Al + aoff + (size_t)(16 * c) * K + k0, &Asl[(wave * ARW + 16 * c) * 32]);
        }
#pragma unroll
        for (int c = 0; c < BRW / 16; ++c) {
            gload16(Wh + woff + (size_t)(16 * c) * K + k0, &Bsh[(wave * BRW + 16 * c) * 32]);
            gload16(Wl + woff + (size_t)(16 * c) * K + k0, &Bsl[(wave * BRW + 16 * c) * 32]);
        }
        __syncthreads();
        short8 ah[MI], al[MI], bh[NJ], bl[NJ];
#pragma unroll
        for (int i = 0; i < MI; ++i) {
            ah[i] = *(const short8*)&Ash[(wm + i * 16 + fr) * 32 + fko];
            al[i] = *(const short8*)&Asl[(wm + i * 16 + fr) * 32 + fko];
        }
#pragma unroll
        for (int j = 0; j < NJ; ++j) {
            bh[j] = *(const short8*)&Bsh[(wn + j * 16 + fr) * 32 + fko];
            bl[j] = *(const short8*)&Bsl[(wn + j * 16 + fr) * 32 + fko];
        }
#pragma unroll
        for (int i = 0; i < MI; ++i)
#pragma unroll
            for (int j = 0; j < NJ; ++j) {
                acc[i][j] = __builtin_amdgcn_mfma_f32_16x16x32_bf16(al[i], bh[j], acc[i][j], 0, 0, 0);
                acc[i][j] = __builtin_amdgcn_mfma_f32_16x16x32_bf16(ah[i], bl[j], acc[i][j], 0, 0, 0);
                acc[i][j] = __builtin_amdgcn_mfma_f32_16x16x32_bf16(ah[i], bh[j], acc[i][j], 0, 0, 0);
            }
        __syncthreads();
    }
    const int r0 = m0 + wm + (lane >> 4) * 4;
#pragma unroll
    for (int i = 0; i < MI; ++i) {
#pragma unroll
        for (int j = 0; j < NJ; ++j) {
            int n = n0 + wn + j * 16 + fr;
            float bv = bias[n];
#pragma unroll
            for (int r = 0; r < 4; ++r) {
                int m = r0 + i * 16 + r;
                size_t idx = (size_t)m * N + n;
                float v = acc[i][j][r] + bv;
                if (ACT) v = fmaxf(v, 0.f);
                Cf[idx] = v;
                if (WCOPY) Ccopy[idx] = v;
                if (WHILO) {
                    unsigned short h = f2bf(v);
                    Hh[idx] = h;
                    Hl[idx] = f2bf(v - bf2f(h));
                }
            }
        }
    }
}

// ---------------- TEL attention: one block per (batch, head); bf16 out ----------------
template <typename T>
__global__ __launch_bounds__(256) void attn_kernel(const T* __restrict__ qkv, unsigned short* __restrict__ outb)
{
    const int b = blockIdx.x >> 3;
    const int h = blockIdx.x & 7;
    __shared__ float qs[32][65], ks[32][65], vs[32][65];
    __shared__ float ps[32][33];
    const int tid = threadIdx.x;
    for (int i = tid; i < 2048; i += 256) {
        int s = i >> 6, d = i & 63;
        size_t base = ((size_t)(b * 32 + s)) * 1536 + h * 64 + d;
        qs[s][d] = ldv(qkv, base);
        ks[s][d] = ldv(qkv, base + 512);
        vs[s][d] = ldv(qkv, base + 1024);
    }
    __syncthreads();
    for (int i = tid; i < 1024; i += 256) {
        int si = i >> 5, sj = i & 31;
        float acc = 0.f;
#pragma unroll 8
        for (int d = 0; d < 64; ++d) acc += qs[si][d] * ks[sj][d];
        ps[si][sj] = acc * 0.125f;
    }
    __syncthreads();
    if (tid < 32) {
        float mx = -1e30f;
        for (int j = 0; j < 32; ++j) mx = fmaxf(mx, ps[tid][j]);
        float sum = 0.f;
        for (int j = 0; j < 32; ++j) { float e = __expf(ps[tid][j] - mx); ps[tid][j] = e; sum += e; }
        float inv = 1.f / sum;
        for (int j = 0; j < 32; ++j) ps[tid][j] *= inv;
    }
    __syncthreads();
    for (int i = tid; i < 2048; i += 256) {
        int s = i >> 6, d = i & 63;
        float acc = 0.f;
#pragma unroll 8
        for (int k = 0; k < 32; ++k) acc += ps[s][k] * vs[k][d];
        outb[((size_t)(b * 32 + s)) * 512 + h * 64 + d] = f2bf(acc);
    }
}

// ---------------- complex self-attention: LDS-resident, grid (128 batch, 2 half) ----------
__global__ __launch_bounds__(256) void cattn2_kernel(const float* __restrict__ LL,
                                                     unsigned short* __restrict__ outHi,
                                                     unsigned short* __restrict__ outLo)
{
    extern __shared__ float Xs[];
    __shared__ float Pr[16][33], Pi[16][33];
    const int b = blockIdx.x, half = blockIdx.y;
    const int tid = threadIdx.x;
    const float* base = LL + (size_t)b * 16384;
    for (int i = tid; i < 16384; i += 256) {
        int c = i >> 9, e = i & 511;
        Xs[e * 32 + ((c ^ e) & 31)] = base[i];
    }
    __syncthreads();
    {
        const int li0 = tid >> 5, li1 = li0 + 8;
        const int ci0 = half * 16 + li0, ci1 = half * 16 + li1;
        const int ck = tid & 31;
        float ar0 = 0.f, ai0 = 0.f, ar1 = 0.f, ai1 = 0.f;
        for (int er = 0; er < 256; ++er) {
            const int sw = er & 31;
            float yr = Xs[er * 32 + ((ck ^ sw) & 31)];
            float yi = Xs[(er + 256) * 32 + ((ck ^ sw) & 31)];
            float xr0 = Xs[er * 32 + ((ci0 ^ sw) & 31)];
            float xi0 = Xs[(er + 256) * 32 + ((ci0 ^ sw) & 31)];
            float xr1 = Xs[er * 32 + ((ci1 ^ sw) & 31)];
            float xi1 = Xs[(er + 256) * 32 + ((ci1 ^ sw) & 31)];
            ar0 += xr0 * yr - xi0 * yi;  ai0 += xr0 * yi + xi0 * yr;
            ar1 += xr1 * yr - xi1 * yi;  ai1 += xr1 * yi + xi1 * yr;
        }
        Pr[li0][ck] = ar0 * 0.0625f;  Pi[li0][ck] = ai0 * 0.0625f;
        Pr[li1][ck] = ar1 * 0.0625f;  Pi[li1][ck] = ai1 * 0.0625f;
    }
    __syncthreads();
    if (tid < 32) {
        int r = tid & 15;
        float (*P)[33] = (tid < 16) ? Pr : Pi;
        float mx = -1e30f;
        for (int j = 0; j < 32; ++j) mx = fmaxf(mx, P[r][j]);
        float s = 0.f;
        for (int j = 0; j < 32; ++j) { float e = __expf(P[r][j] - mx); P[r][j] = e; s += e; }
        float inv = 1.f / s;
        for (int j = 0; j < 32; ++j) P[r][j] *= inv;
    }
    __syncthreads();
    const int er = tid;
    const int sw = er & 31;
    float accr[16], acci[16];
#pragma unroll
    for (int t = 0; t < 16; ++t) { accr[t] = 0.f; acci[t] = 0.f; }
    for (int k = 0; k < 32; ++k) {
        float yr = Xs[er * 32 + ((k ^ sw) & 31)];
        float yi = Xs[(er + 256) * 32 + ((k ^ sw) & 31)];
#pragma unroll
        for (int t = 0; t < 16; ++t) {
            float pr = Pr[t][k], pi = Pi[t][k];
            accr[t] += pr * yr - pi * yi;
            acci[t] += pr * yi + pi * yr;
        }
    }
#pragma unroll
    for (int t = 0; t < 16; ++t) {
        int c = half * 16 + t;
        float vr = Xs[er * 32 + ((c ^ sw) & 31)] + accr[t];
        float vi = Xs[(er + 256) * 32 + ((c ^ sw) & 31)] + acci[t];
        size_t ir = (size_t)b * 16384 + (size_t)c * 512 + er;
        unsigned short hr = f2bf(vr), hi2 = f2bf(vi);
        outHi[ir] = hr;        outLo[ir] = f2bf(vr - bf2f(hr));
        outHi[ir + 256] = hi2; outLo[ir + 256] = f2bf(vi - bf2f(hi2));
    }
}

// ---------------- residual add + LayerNorm (512), optional 2nd summand + bf16 copy ------
template <int WBF, int Y2>
__global__ __launch_bounds__(256) void add_ln_kernel(const float* __restrict__ resid, const float* __restrict__ y,
                                                     const float* __restrict__ y2,
                                                     const float* __restrict__ w, const float* __restrict__ b,
                                                     float* __restrict__ outf, unsigned short* __restrict__ outb)
{
    const int row = blockIdx.x;
    const int tid = threadIdx.x;
    const size_t base = (size_t)row * 512;
    float v0 = resid[base + tid] + y[base + tid];
    float v1 = resid[base + 256 + tid] + y[base + 256 + tid];
    if (Y2) { v0 += y2[base + tid]; v1 += y2[base + 256 + tid]; }
    float s = v0 + v1, q = v0 * v0 + v1 * v1;
    for (int off = 32; off; off >>= 1) { s += __shfl_down(s, off); q += __shfl_down(q, off); }
    __shared__ float sw[4], qw[4], ms, is;
    int wid = tid >> 6, lane = tid & 63;
    if (lane == 0) { sw[wid] = s; qw[wid] = q; }
    __syncthreads();
    if (tid == 0) {
        float S = sw[0] + sw[1] + sw[2] + sw[3];
        float Q = qw[0] + qw[1] + qw[2] + qw[3];
        float m = S * (1.f / 512.f);
        ms = m;
        is = rsqrtf(Q * (1.f / 512.f) - m * m + 1e-5f);
    }
    __syncthreads();
    float m = ms, inv = is;
    float o0 = (v0 - m) * inv * w[tid] + b[tid];
    float o1 = (v1 - m) * inv * w[256 + tid] + b[256 + tid];
    outf[base + tid] = o0;
    outf[base + 256 + tid] = o1;
    if (WBF) { outb[base + tid] = f2bf(o0); outb[base + 256 + tid] = f2bf(o1); }
}

// ---------------- relu + LayerNorm over (C,S)=16384 per batch, optional final add -------
template <int ADDF>
__global__ __launch_bounds__(256) void relu_bln_kernel(const float* __restrict__ xin,
                                                       const float* __restrict__ w, const float* __restrict__ b,
                                                       const float* __restrict__ addsrc,
                                                       float* __restrict__ out)
{
    const int bb = blockIdx.x;
    const int tid = threadIdx.x;
    const float* xp = xin + (size_t)bb * 16384;
    float s = 0.f, q = 0.f;
    for (int i = tid; i < 16384; i += 256) { float v = fmaxf(xp[i], 0.f); s += v; q += v * v; }
    for (int off = 32; off; off >>= 1) { s += __shfl_down(s, off); q += __shfl_down(q, off); }
    __shared__ float sw[4], qw[4], ms, is;
    int wid = tid >> 6, lane = tid & 63;
    if (lane == 0) { sw[wid] = s; qw[wid] = q; }
    __syncthreads();
    if (tid == 0) {
        float S = sw[0] + sw[1] + sw[2] + sw[3];
        float Q = qw[0] + qw[1] + qw[2] + qw[3];
        float m = S * (1.f / 16384.f);
        ms = m;
        is = rsqrtf(Q * (1.f / 16384.f) - m * m + 1e-5f);
    }
    __syncthreads();
    float m = ms, inv = is;
    const float* ap = ADDF ? (addsrc + (size_t)bb * 16384) : nullptr;
    float* op = out + (size_t)bb * 16384;
    for (int i = tid; i < 16384; i += 256) {
        float v = fmaxf(xp[i], 0.f);
        float o = (v - m) * inv * w[i] + b[i];
        if (ADDF) o += ap[i];
        op[i] = o;
    }
}

extern "C" void kernel_launch(void* const* d_in, const int* in_sizes, int n_in,
                              void* d_out, int out_size, void* d_ws, size_t ws_size,
                              hipStream_t stream)
{
    (void)in_sizes; (void)n_in; (void)out_size; (void)ws_size;
    const float* x        = (const float*)d_in[0];
    const float* t_in_w   = (const float*)d_in[1];
    const float* t_in_b   = (const float*)d_in[2];
    const float* t_out_w  = (const float*)d_in[3];
    const float* t_out_b  = (const float*)d_in[4];
    const float* t_ln1_w  = (const float*)d_in[5];
    const float* t_ln1_b  = (const float*)d_in[6];
    const float* t_lin1_w = (const float*)d_in[7];
    const float* t_lin1_b = (const float*)d_in[8];
    const float* t_lin2_w = (const float*)d_in[9];
    const float* t_lin2_b = (const float*)d_in[10];
    const float* t_ln2_w  = (const float*)d_in[11];
    const float* t_ln2_b  = (const float*)d_in[12];
    const float* r_in_w   = (const float*)d_in[13];
    const float* r_in_b   = (const float*)d_in[14];
    const float* r_out_w  = (const float*)d_in[15];
    const float* r_out_b  = (const float*)d_in[16];
    const float* r_ln1_w  = (const float*)d_in[17];
    const float* r_ln1_b  = (const float*)d_in[18];
    const float* r_lin1_w = (const float*)d_in[19];
    const float* r_lin1_b = (const float*)d_in[20];
    const float* r_lin2_w = (const float*)d_in[21];
    const float* r_lin2_b = (const float*)d_in[22];
    const float* r_ln2_w  = (const float*)d_in[23];
    const float* r_ln2_b  = (const float*)d_in[24];
    const float* lc_w     = (const float*)d_in[25];
    const float* lc_b     = (const float*)d_in[26];
    const float* up1_w    = (const float*)d_in[27];
    const float* up1_b    = (const float*)d_in[28];
    const float* up2_w    = (const float*)d_in[29];
    const float* up2_b    = (const float*)d_in[30];
    const float* n1_w     = (const float*)d_in[31];
    const float* n1_b     = (const float*)d_in[32];
    const float* n2_w     = (const float*)d_in[33];
    const float* n2_b     = (const float*)d_in[34];
    const float* l1_re    = (const float*)d_in[35];
    const float* l1_im    = (const float*)d_in[36];
    const float* lb1_re   = (const float*)d_in[39];
    const float* lb1_im   = (const float*)d_in[40];

    float* outp = (float*)d_out;

    // ---- workspace (float offsets; total 21,774,336 f = 87.1 MB, validated size) ----
    float* WS   = (float*)d_ws;
    float* WaF  = WS + 0;          // 262144 f32 Wa; later WmH/WmL ushort
    float* WmF  = WS + 262144;     // 262144 f32 Wm
    float* LB   = WS + 524288;     // 16384 ([0:512) lb bias)
    float* BIGf = WS + 540672;     // 6291456: r-qkv f32 | qkv/f1 bf16 [0:4194304) | BbF [4194304:)
    float* Cc   = WS + 6832128;    // 2097152: fa_hi/fa_lo u halves -> AabU -> x1r -> AabU -> x1
    float* Ee   = WS + 8929280;    // 2097152: tab(prep) -> t-out partial -> t-lin2 partial -> x2
    float* LLp  = WS + 11026432;   // 2097152: low f32 -> rinLo alias -> r-out/lin2 partial -> x2r -> rf
    float* FAp  = WS + 13123584;   // 2097152: WaH/WaL(prep) -> fa f32
    float* U1f  = WS + 15220736;   // 1048576 u2: x_hi -> x1b
    float* U2f  = WS + 16269312;   // 1048576 u2: x_lo -> LL_hi -> u1b -> x1rb
    float* U3f  = WS + 17317888;   // 1048576 u2: LL_lo
    float* WBf  = WS + 18366464;   // 3407872: ushort weights (6815744)

    float* BbF  = BIGf + 4194304;
    float* tabC = Ee;
    float* tabS = Ee + 131072;
    unsigned short* BIGu   = (unsigned short*)BIGf;
    unsigned short* AabU   = (unsigned short*)Cc;              // 2M u = Cc lower half
    unsigned short* FaHiU  = (unsigned short*)Cc;              // fa_hi (freq phase)
    unsigned short* FaLoU  = (unsigned short*)(Cc + 1048576);  // fa_lo (freq phase)
    unsigned short* rinLoU = (unsigned short*)LLp;             // 786432 u
    unsigned short* WaHu   = (unsigned short*)FAp;
    unsigned short* WaLu   = (unsigned short*)(FAp + 131072);
    unsigned short* WmHu   = (unsigned short*)WaF;
    unsigned short* WmLu   = (unsigned short*)(WaF + 131072);
    unsigned short* U1u    = (unsigned short*)U1f;
    unsigned short* U2u    = (unsigned short*)U2f;
    unsigned short* U3u    = (unsigned short*)U3f;
    unsigned short* WB     = (unsigned short*)WBf;

    unsigned short* w_tin  = WB + 0;        // 1536x512
    unsigned short* w_tout = WB + 786432;   // 512x512
    unsigned short* w_tl1  = WB + 1048576;  // 2048x512
    unsigned short* w_tl2  = WB + 2097152;  // 512x2048
    unsigned short* w_rin  = WB + 3145728;  // 1536x512
    unsigned short* w_rout = WB + 3932160;  // 512x512
    unsigned short* w_rl1  = WB + 4194304;  // 2048x512
    unsigned short* w_rl2  = WB + 5242880;  // 512x2048
    unsigned short* w_up1  = WB + 6291456;  // 512x512
    unsigned short* w_up2  = WB + 6553600;  // 512x512

    dim3 blk(256);

    // ---- prep ----
    tab_kernel<<<dim3(512), blk, 0, stream>>>(tabC, tabS);
    wa_kernel<<<dim3(512, 2), blk, 0, stream>>>(l1_re, l1_im, tabC, tabS, WaF);
    wm_kernel<<<dim3(512, 2), blk, 0, stream>>>(lc_w, tabC, tabS, WmF);
    cvt_hilo_kernel<<<dim3(1024), blk, 0, stream>>>(WaF, WaHu, WaLu, 262144);
    cvt_hilo_kernel<<<dim3(1024), blk, 0, stream>>>(WmF, WmHu, WmLu, 262144);
    lbpack_kernel<<<dim3(2), blk, 0, stream>>>(lb1_re, lb1_im, LB);
    wcvt_kernel<<<dim3(26624), blk, 0, stream>>>(t_in_w, t_out_w, t_lin1_w, t_lin2_w,
                                                 r_in_w, r_out_w, r_lin1_w, r_lin2_w,
                                                 up1_w, up2_w, WB);
    xsplit_kernel<<<dim3(2048), blk, 0, stream>>>(x, U1u, U2u, outp + NOUT, NOUT);  // x hi/lo + down_x

    // ---- freq branch ----
    gemm_mfma3<64,64,1,0,0><<<dim3(8, 64), blk, 0, stream>>>(U1u, U2u, WaHu, WaLu, LB,
                                                             LLp, nullptr, nullptr, nullptr, 512, 512);
    cattn2_kernel<<<dim3(128, 2), blk, 65536, stream>>>(LLp, U2u, U3u);              // LL hi/lo
    gemm_mfma3<64,64,0,1,1><<<dim3(8, 64), blk, 0, stream>>>(U2u, U3u, WmHu, WmLu, lc_b,
                                                             FAp, outp + 2 * NOUT, FaHiU, FaLoU, 512, 512);
    cvt_lo_kernel<<<dim3(768), blk, 0, stream>>>(r_in_w, w_rin, rinLoU, 786432);     // rin lo

    // ---- upsample (fa_hi) ----
    gemm_mfma<64,64,0,0,1,0><<<dim3(8, 64), blk, 0, stream>>>(FaHiU, w_up1, up1_b, nullptr, nullptr, U2u, 512, 512);
    gemm_mfma<64,64,0,1,0,0><<<dim3(8, 64), blk, 0, stream>>>(U2u, w_up2, up2_b, outp + 3 * NOUT, nullptr, nullptr, 512, 512);

    // ---- r-TEL on fa (fused hi/lo qkv) ----
    gemm_mfma3<64,128,0,0,0><<<dim3(12, 64), blk, 0, stream>>>(FaHiU, FaLoU, w_rin, rinLoU, r_in_b,
                                                               BIGf, nullptr, nullptr, nullptr, 1536, 512);
    attn_kernel<float><<<dim3(1024), blk, 0, stream>>>(BIGf, AabU);
    gemm_mfma<64,64,0,1,0,1><<<dim3(8, 64, 2), blk, 0, stream>>>(AabU, w_rout, r_out_b, BbF, LLp, nullptr, 512, 512);
    add_ln_kernel<1,1><<<dim3(4096), blk, 0, stream>>>(FAp, BbF, LLp, r_ln1_w, r_ln1_b, Cc, U2u);  // x1r (+bf16)
    gemm_mfma<64,128,1,0,1,0><<<dim3(16, 64), blk, 0, stream>>>(U2u, w_rl1, r_lin1_b, nullptr, nullptr, BIGu, 2048, 512);
    gemm_mfma<64,64,0,1,0,1><<<dim3(8, 64, 2), blk, 0, stream>>>(BIGu, w_rl2, r_lin2_b, BbF, LLp, nullptr, 512, 2048);
    add_ln_kernel<0,1><<<dim3(4096), blk, 0, stream>>>(Cc, BbF, LLp, r_ln2_w, r_ln2_b, LLp, nullptr); // x2r
    relu_bln_kernel<0><<<dim3(128), blk, 0, stream>>>(LLp, n2_w, n2_b, nullptr, LLp);                 // rf

    // ---- t-TEL on x ----
    gemm_mfma<64,128,0,0,1,0><<<dim3(12, 64), blk, 0, stream>>>(U1u, w_tin, t_in_b, nullptr, nullptr, BIGu, 1536, 512);
    attn_kernel<unsigned short><<<dim3(1024), blk, 0, stream>>>(BIGu, AabU);
    gemm_mfma<64,64,0,1,0,1><<<dim3(8, 64, 2), blk, 0, stream>>>(AabU, w_tout, t_out_b, BbF, Ee, nullptr, 512, 512);
    add_ln_kernel<1,1><<<dim3(4096), blk, 0, stream>>>(x, BbF, Ee, t_ln1_w, t_ln1_b, Cc, U1u);        // x1 (+bf16)
    gemm_mfma<64,128,1,0,1,0><<<dim3(16, 64), blk, 0, stream>>>(U1u, w_tl1, t_lin1_b, nullptr, nullptr, BIGu, 2048, 512);
    gemm_mfma<64,64,0,1,0,1><<<dim3(8, 64, 2), blk, 0, stream>>>(BIGu, w_tl2, t_lin2_b, BbF, Ee, nullptr, 512, 2048);
    add_ln_kernel<0,1><<<dim3(4096), blk, 0, stream>>>(Cc, BbF, Ee, t_ln2_w, t_ln2_b, Ee, nullptr);   // x2
    relu_bln_kernel<1><<<dim3(128), blk, 0, stream>>>(Ee, n1_w, n1_b, LLp, outp);                     // res = df + rf
}